// Round 1
// baseline (9067.353 us; speedup 1.0000x reference)
//
#include <hip/hip_runtime.h>

#define NU 50000
#define NI 50000
#define NE 800000
#define NLBL 200000
#define DIN 128
#define HID 256
#define DOUT 128

// ---------------- degree count ----------------
__global__ void degree_kernel(const int* __restrict__ dst, float* __restrict__ deg, int n) {
    int i = blockIdx.x * blockDim.x + threadIdx.x;
    if (i < n) atomicAdd(&deg[dst[i]], 1.0f);
}

// ---------------- scatter-add of features along edges ----------------
// one thread per (edge, float4 chunk)
template <int D>
__global__ void scatter_kernel(const int* __restrict__ src, const int* __restrict__ dst,
                               const float* __restrict__ x, float* __restrict__ agg, int nE) {
    constexpr int C = D / 4;
    long long idx = (long long)blockIdx.x * blockDim.x + threadIdx.x;
    int e = (int)(idx / C);
    int c = (int)(idx % C);
    if (e >= nE) return;
    int s = src[e];
    int d = dst[e];
    const float4 v = ((const float4*)(x + (size_t)s * D))[c];
    float* p = agg + (size_t)d * D + (size_t)c * 4;
    atomicAdd(p + 0, v.x);
    atomicAdd(p + 1, v.y);
    atomicAdd(p + 2, v.z);
    atomicAdd(p + 3, v.w);
}

// ---------------- fused GEMM: C = rowscale(A1)@W1 + A2@W2 + bias ----------------
// rowscale(A1)[i,:] = A1[i,:] / max(deg[i],1)  (deg==nullptr -> no scale)
// A row-major [M,K*], W row-major [K*,N], C row-major [M,N]. K1,K2 % 16 == 0, N % 64 == 0.
__global__ __launch_bounds__(256) void gemm_fused(
    const float* __restrict__ A1, const float* __restrict__ deg,
    const float* __restrict__ W1, int K1,
    const float* __restrict__ A2, const float* __restrict__ W2, int K2,
    const float* __restrict__ bias,
    float* __restrict__ C, int M, int N) {
    __shared__ float As[16][65];
    __shared__ float Bs[16][68];
    const int tid = threadIdx.x;
    const int tx = tid & 15, ty = tid >> 4;
    const int bm = blockIdx.y * 64, bn = blockIdx.x * 64;
    float acc[4][4] = {{0.f}};

    const int la_row = tid >> 2;        // 0..63
    const int la_col = (tid & 3) * 4;   // 0,4,8,12
    const int arow = bm + la_row;
    const int lb_row = tid >> 4;        // 0..15
    const int lb_col = (tid & 15) * 4;  // 0..60

    for (int part = 0; part < 2; ++part) {
        const float* A = part ? A2 : A1;
        const float* W = part ? W2 : W1;
        const int K = part ? K2 : K1;
        float s = 1.0f;
        if (part == 0 && deg != nullptr)
            s = 1.0f / fmaxf((arow < M) ? deg[arow] : 1.0f, 1.0f);
        const float* Arow = A + (size_t)arow * K;
        for (int k0 = 0; k0 < K; k0 += 16) {
            float4 av = make_float4(0.f, 0.f, 0.f, 0.f);
            if (arow < M) av = *(const float4*)(Arow + k0 + la_col);
            As[la_col + 0][la_row] = av.x * s;
            As[la_col + 1][la_row] = av.y * s;
            As[la_col + 2][la_row] = av.z * s;
            As[la_col + 3][la_row] = av.w * s;
            const float4 bv = *(const float4*)(W + (size_t)(k0 + lb_row) * N + bn + lb_col);
            *(float4*)(&Bs[lb_row][lb_col]) = bv;
            __syncthreads();
#pragma unroll
            for (int kk = 0; kk < 16; ++kk) {
                float a[4], b[4];
#pragma unroll
                for (int i = 0; i < 4; ++i) a[i] = As[kk][ty * 4 + i];
#pragma unroll
                for (int j = 0; j < 4; ++j) b[j] = Bs[kk][tx * 4 + j];
#pragma unroll
                for (int i = 0; i < 4; ++i)
#pragma unroll
                    for (int j = 0; j < 4; ++j) acc[i][j] += a[i] * b[j];
            }
            __syncthreads();
        }
    }
#pragma unroll
    for (int i = 0; i < 4; ++i) {
        int r = bm + ty * 4 + i;
        if (r >= M) continue;
#pragma unroll
        for (int j = 0; j < 4; ++j) {
            int cn = bn + tx * 4 + j;
            C[(size_t)r * N + cn] = acc[i][j] + bias[cn];
        }
    }
}

// ---------------- decode: pred[e] = dot(z_user[lbl0[e]], z_item[lbl1[e]]) ----------------
// one wave (64 lanes) per edge, 2 floats per lane
__global__ void decode_kernel(const int* __restrict__ lbl, const float* __restrict__ zu,
                              const float* __restrict__ zi, float* __restrict__ out, int n) {
    int gid = blockIdx.x * blockDim.x + threadIdx.x;
    int e = gid >> 6;
    int lane = gid & 63;
    if (e >= n) return;
    int u = lbl[e];
    int it = lbl[n + e];
    const float2 a = *(const float2*)(zu + (size_t)u * DOUT + lane * 2);
    const float2 b = *(const float2*)(zi + (size_t)it * DOUT + lane * 2);
    float s = a.x * b.x + a.y * b.y;
#pragma unroll
    for (int off = 32; off > 0; off >>= 1) s += __shfl_down(s, off, 64);
    if (lane == 0) out[e] = s;
}

extern "C" void kernel_launch(void* const* d_in, const int* in_sizes, int n_in,
                              void* d_out, int out_size, void* d_ws, size_t ws_size,
                              hipStream_t stream) {
    const float* x_user = (const float*)d_in[0];
    const float* x_item = (const float*)d_in[1];
    const int* edge_ui = (const int*)d_in[2];   // [2, NE]: row0=src(user), row1=dst(item)
    const int* edge_iu = (const int*)d_in[3];   // [2, NE]: row0=src(item), row1=dst(user)
    const int* edge_lbl = (const int*)d_in[4];  // [2, NLBL]
    const float* w_msg_ui0 = (const float*)d_in[5];
    const float* b_ui0 = (const float*)d_in[6];
    const float* w_root_ui0 = (const float*)d_in[7];
    const float* w_msg_iu0 = (const float*)d_in[8];
    const float* b_iu0 = (const float*)d_in[9];
    const float* w_root_iu0 = (const float*)d_in[10];
    const float* w_msg_ui1 = (const float*)d_in[11];
    const float* b_ui1 = (const float*)d_in[12];
    const float* w_root_ui1 = (const float*)d_in[13];
    const float* w_msg_iu1 = (const float*)d_in[14];
    const float* b_iu1 = (const float*)d_in[15];
    const float* w_root_iu1 = (const float*)d_in[16];
    const float* w_lin_u = (const float*)d_in[17];  // [2*HID, DOUT]
    const float* b_lin_u = (const float*)d_in[18];
    const float* w_lin_i = (const float*)d_in[19];
    const float* b_lin_i = (const float*)d_in[20];
    float* out = (float*)d_out;

    float* ws = (float*)d_ws;
    float* user0 = ws;
    float* item0 = user0 + (size_t)NU * HID;
    float* user1 = item0 + (size_t)NI * HID;
    float* item1 = user1 + (size_t)NU * HID;
    float* scratch = item1 + (size_t)NI * HID;  // NU*HID floats; mean buffer, later z_user|z_item
    float* deg_u = scratch + (size_t)NU * HID;
    float* deg_i = deg_u + NU;

    // ---- degrees (deg_u, deg_i adjacent -> one memset) ----
    hipMemsetAsync(deg_u, 0, (size_t)(NU + NI) * sizeof(float), stream);
    degree_kernel<<<(NE + 255) / 256, 256, 0, stream>>>(edge_ui + NE, deg_i, NE);
    degree_kernel<<<(NE + 255) / 256, 256, 0, stream>>>(edge_iu + NE, deg_u, NE);

    // ---- layer 0: item0 = mean_{u->i}(x_user) @ Wm + b + x_item @ Wr ----
    hipMemsetAsync(scratch, 0, (size_t)NI * DIN * sizeof(float), stream);
    scatter_kernel<DIN><<<(NE * (DIN / 4) + 255) / 256, 256, 0, stream>>>(
        edge_ui, edge_ui + NE, x_user, scratch, NE);
    gemm_fused<<<dim3(HID / 64, (NI + 63) / 64), 256, 0, stream>>>(
        scratch, deg_i, w_msg_ui0, DIN, x_item, w_root_ui0, DIN, b_ui0, item0, NI, HID);

    // ---- layer 0: user0 ----
    hipMemsetAsync(scratch, 0, (size_t)NU * DIN * sizeof(float), stream);
    scatter_kernel<DIN><<<(NE * (DIN / 4) + 255) / 256, 256, 0, stream>>>(
        edge_iu, edge_iu + NE, x_item, scratch, NE);
    gemm_fused<<<dim3(HID / 64, (NU + 63) / 64), 256, 0, stream>>>(
        scratch, deg_u, w_msg_iu0, DIN, x_user, w_root_iu0, DIN, b_iu0, user0, NU, HID);

    // ---- layer 1: item1 = mean_{u->i}(user0) @ Wm + b + item0 @ Wr ----
    hipMemsetAsync(scratch, 0, (size_t)NI * HID * sizeof(float), stream);
    scatter_kernel<HID><<<(NE * (HID / 4) + 255) / 256, 256, 0, stream>>>(
        edge_ui, edge_ui + NE, user0, scratch, NE);
    gemm_fused<<<dim3(HID / 64, (NI + 63) / 64), 256, 0, stream>>>(
        scratch, deg_i, w_msg_ui1, HID, item0, w_root_ui1, HID, b_ui1, item1, NI, HID);

    // ---- layer 1: user1 ----
    hipMemsetAsync(scratch, 0, (size_t)NU * HID * sizeof(float), stream);
    scatter_kernel<HID><<<(NE * (HID / 4) + 255) / 256, 256, 0, stream>>>(
        edge_iu, edge_iu + NE, item0, scratch, NE);
    gemm_fused<<<dim3(HID / 64, (NU + 63) / 64), 256, 0, stream>>>(
        scratch, deg_u, w_msg_iu1, HID, user0, w_root_iu1, HID, b_iu1, user1, NU, HID);

    // ---- JK concat + per-type linear (scratch reused as z_user | z_item) ----
    float* z_user = scratch;
    float* z_item = scratch + (size_t)NU * DOUT;
    gemm_fused<<<dim3(DOUT / 64, (NU + 63) / 64), 256, 0, stream>>>(
        user0, nullptr, w_lin_u, HID, user1, w_lin_u + (size_t)HID * DOUT, HID, b_lin_u,
        z_user, NU, DOUT);
    gemm_fused<<<dim3(DOUT / 64, (NI + 63) / 64), 256, 0, stream>>>(
        item0, nullptr, w_lin_i, HID, item1, w_lin_i + (size_t)HID * DOUT, HID, b_lin_i,
        z_item, NI, DOUT);

    // ---- decode ----
    decode_kernel<<<((size_t)NLBL * 64 + 255) / 256, 256, 0, stream>>>(
        edge_lbl, z_user, z_item, out, NLBL);
}

// Round 2
// 1550.945 us; speedup vs baseline: 5.8463x; 5.8463x over previous
//
#include <hip/hip_runtime.h>

#define NU 50000
#define NI 50000
#define NE 800000
#define NLBL 200000
#define DIN 128
#define HID 256
#define DOUT 128

// ================= CSR build =================
__global__ void hist_kernel(const int* __restrict__ dst, int* __restrict__ cnt, int n) {
    int i = blockIdx.x * blockDim.x + threadIdx.x;
    if (i < n) atomicAdd(&cnt[dst[i]], 1);
}

// single-workgroup exclusive scan, in place. 1024 threads.
__global__ __launch_bounds__(1024) void scan_kernel(int* __restrict__ data, int n) {
    __shared__ int part[16];
    __shared__ int tot_sh;
    const int tid = threadIdx.x;
    const int lane = tid & 63;
    const int wv = tid >> 6;
    int cv = 0;
    for (int base = 0; base < n; base += 1024) {
        int i = base + tid;
        int v0 = (i < n) ? data[i] : 0;
        int v = v0;
#pragma unroll
        for (int off = 1; off < 64; off <<= 1) {
            int t = __shfl_up(v, off, 64);
            if (lane >= off) v += t;
        }
        if (lane == 63) part[wv] = v;
        __syncthreads();
        if (tid < 16) {
            int p = part[tid];
            int q = p;
#pragma unroll
            for (int off = 1; off < 16; off <<= 1) {
                int t = __shfl_up(q, off, 16);
                if (tid >= off) q += t;
            }
            part[tid] = q - p;  // exclusive
            if (tid == 15) tot_sh = q;
        }
        __syncthreads();
        if (i < n) data[i] = v - v0 + part[wv] + cv;
        cv += tot_sh;
        __syncthreads();
    }
}

// fill: advances rowpos from start-offsets to end-offsets
__global__ void fill_kernel(const int* __restrict__ src, const int* __restrict__ dst,
                            int* __restrict__ rowpos, int* __restrict__ csr, int n) {
    int e = blockIdx.x * blockDim.x + threadIdx.x;
    if (e < n) {
        int p = atomicAdd(&rowpos[dst[e]], 1);
        csr[p] = src[e];
    }
}

// ================= gather-based mean aggregation =================
// one wave per dst node; endptr[i] = CSR row end, start = endptr[i-1] (0 for i==0)
template <int D>
__global__ __launch_bounds__(256) void agg_mean(const int* __restrict__ endptr,
                                                const int* __restrict__ csr,
                                                const float* __restrict__ x,
                                                float* __restrict__ out, int n) {
    int w = (int)((blockIdx.x * (unsigned)blockDim.x + threadIdx.x) >> 6);
    int lane = threadIdx.x & 63;
    if (w >= n) return;
    int s0 = (w == 0) ? 0 : endptr[w - 1];
    int s1 = endptr[w];
    float sc = (s1 > s0) ? 1.0f / (float)(s1 - s0) : 0.0f;
    if constexpr (D == 128) {
        float2 a0 = make_float2(0.f, 0.f), a1 = make_float2(0.f, 0.f);
        int e = s0;
        for (; e + 1 < s1; e += 2) {
            int iA = __builtin_amdgcn_readfirstlane(csr[e]);
            int iB = __builtin_amdgcn_readfirstlane(csr[e + 1]);
            float2 vA = *(const float2*)(x + (size_t)iA * D + lane * 2);
            float2 vB = *(const float2*)(x + (size_t)iB * D + lane * 2);
            a0.x += vA.x; a0.y += vA.y;
            a1.x += vB.x; a1.y += vB.y;
        }
        if (e < s1) {
            int iA = __builtin_amdgcn_readfirstlane(csr[e]);
            float2 vA = *(const float2*)(x + (size_t)iA * D + lane * 2);
            a0.x += vA.x; a0.y += vA.y;
        }
        float2 r = make_float2((a0.x + a1.x) * sc, (a0.y + a1.y) * sc);
        *(float2*)(out + (size_t)w * D + lane * 2) = r;
    } else {
        float4 a0 = make_float4(0.f, 0.f, 0.f, 0.f), a1 = a0;
        int e = s0;
        for (; e + 1 < s1; e += 2) {
            int iA = __builtin_amdgcn_readfirstlane(csr[e]);
            int iB = __builtin_amdgcn_readfirstlane(csr[e + 1]);
            float4 vA = *(const float4*)(x + (size_t)iA * D + lane * 4);
            float4 vB = *(const float4*)(x + (size_t)iB * D + lane * 4);
            a0.x += vA.x; a0.y += vA.y; a0.z += vA.z; a0.w += vA.w;
            a1.x += vB.x; a1.y += vB.y; a1.z += vB.z; a1.w += vB.w;
        }
        if (e < s1) {
            int iA = __builtin_amdgcn_readfirstlane(csr[e]);
            float4 vA = *(const float4*)(x + (size_t)iA * D + lane * 4);
            a0.x += vA.x; a0.y += vA.y; a0.z += vA.z; a0.w += vA.w;
        }
        float4 r = make_float4((a0.x + a1.x) * sc, (a0.y + a1.y) * sc,
                               (a0.z + a1.z) * sc, (a0.w + a1.w) * sc);
        *(float4*)(out + (size_t)w * D + lane * 4) = r;
    }
}

// ================= fallback: atomic scatter path =================
__global__ void degree_kernel(const int* __restrict__ dst, float* __restrict__ deg, int n) {
    int i = blockIdx.x * blockDim.x + threadIdx.x;
    if (i < n) atomicAdd(&deg[dst[i]], 1.0f);
}

template <int D>
__global__ void scatter_kernel(const int* __restrict__ src, const int* __restrict__ dst,
                               const float* __restrict__ x, float* __restrict__ agg, int nE) {
    constexpr int C = D / 4;
    long long idx = (long long)blockIdx.x * blockDim.x + threadIdx.x;
    int e = (int)(idx / C);
    int c = (int)(idx % C);
    if (e >= nE) return;
    int s = src[e];
    int d = dst[e];
    const float4 v = ((const float4*)(x + (size_t)s * D))[c];
    float* p = agg + (size_t)d * D + (size_t)c * 4;
    atomicAdd(p + 0, v.x);
    atomicAdd(p + 1, v.y);
    atomicAdd(p + 2, v.z);
    atomicAdd(p + 3, v.w);
}

// ================= fused GEMM: C = rowscale(A1)@W1 + A2@W2 + bias =================
__global__ __launch_bounds__(256) void gemm_fused(
    const float* __restrict__ A1, const float* __restrict__ deg,
    const float* __restrict__ W1, int K1,
    const float* __restrict__ A2, const float* __restrict__ W2, int K2,
    const float* __restrict__ bias,
    float* __restrict__ C, int M, int N) {
    __shared__ float As[16][65];
    __shared__ float Bs[16][68];
    const int tid = threadIdx.x;
    const int tx = tid & 15, ty = tid >> 4;
    const int bm = blockIdx.y * 64, bn = blockIdx.x * 64;
    float acc[4][4] = {{0.f}};

    const int la_row = tid >> 2;
    const int la_col = (tid & 3) * 4;
    const int arow = bm + la_row;
    const int lb_row = tid >> 4;
    const int lb_col = (tid & 15) * 4;

    for (int part = 0; part < 2; ++part) {
        const float* A = part ? A2 : A1;
        const float* W = part ? W2 : W1;
        const int K = part ? K2 : K1;
        float s = 1.0f;
        if (part == 0 && deg != nullptr)
            s = 1.0f / fmaxf((arow < M) ? deg[arow] : 1.0f, 1.0f);
        const float* Arow = A + (size_t)arow * K;
        for (int k0 = 0; k0 < K; k0 += 16) {
            float4 av = make_float4(0.f, 0.f, 0.f, 0.f);
            if (arow < M) av = *(const float4*)(Arow + k0 + la_col);
            As[la_col + 0][la_row] = av.x * s;
            As[la_col + 1][la_row] = av.y * s;
            As[la_col + 2][la_row] = av.z * s;
            As[la_col + 3][la_row] = av.w * s;
            const float4 bv = *(const float4*)(W + (size_t)(k0 + lb_row) * N + bn + lb_col);
            *(float4*)(&Bs[lb_row][lb_col]) = bv;
            __syncthreads();
#pragma unroll
            for (int kk = 0; kk < 16; ++kk) {
                float a[4], b[4];
#pragma unroll
                for (int i = 0; i < 4; ++i) a[i] = As[kk][ty * 4 + i];
#pragma unroll
                for (int j = 0; j < 4; ++j) b[j] = Bs[kk][tx * 4 + j];
#pragma unroll
                for (int i = 0; i < 4; ++i)
#pragma unroll
                    for (int j = 0; j < 4; ++j) acc[i][j] += a[i] * b[j];
            }
            __syncthreads();
        }
    }
#pragma unroll
    for (int i = 0; i < 4; ++i) {
        int r = bm + ty * 4 + i;
        if (r >= M) continue;
#pragma unroll
        for (int j = 0; j < 4; ++j) {
            int cn = bn + tx * 4 + j;
            C[(size_t)r * N + cn] = acc[i][j] + bias[cn];
        }
    }
}

// ================= decode =================
__global__ void decode_kernel(const int* __restrict__ lbl, const float* __restrict__ zu,
                              const float* __restrict__ zi, float* __restrict__ out, int n) {
    int gid = blockIdx.x * blockDim.x + threadIdx.x;
    int e = gid >> 6;
    int lane = gid & 63;
    if (e >= n) return;
    int u = lbl[e];
    int it = lbl[n + e];
    const float2 a = *(const float2*)(zu + (size_t)u * DOUT + lane * 2);
    const float2 b = *(const float2*)(zi + (size_t)it * DOUT + lane * 2);
    float s = a.x * b.x + a.y * b.y;
#pragma unroll
    for (int off = 32; off > 0; off >>= 1) s += __shfl_down(s, off, 64);
    if (lane == 0) out[e] = s;
}

extern "C" void kernel_launch(void* const* d_in, const int* in_sizes, int n_in,
                              void* d_out, int out_size, void* d_ws, size_t ws_size,
                              hipStream_t stream) {
    const float* x_user = (const float*)d_in[0];
    const float* x_item = (const float*)d_in[1];
    const int* edge_ui = (const int*)d_in[2];   // row0=src(user), row1=dst(item)
    const int* edge_iu = (const int*)d_in[3];   // row0=src(item), row1=dst(user)
    const int* edge_lbl = (const int*)d_in[4];
    const float* w_msg_ui0 = (const float*)d_in[5];
    const float* b_ui0 = (const float*)d_in[6];
    const float* w_root_ui0 = (const float*)d_in[7];
    const float* w_msg_iu0 = (const float*)d_in[8];
    const float* b_iu0 = (const float*)d_in[9];
    const float* w_root_iu0 = (const float*)d_in[10];
    const float* w_msg_ui1 = (const float*)d_in[11];
    const float* b_ui1 = (const float*)d_in[12];
    const float* w_root_ui1 = (const float*)d_in[13];
    const float* w_msg_iu1 = (const float*)d_in[14];
    const float* b_iu1 = (const float*)d_in[15];
    const float* w_root_iu1 = (const float*)d_in[16];
    const float* w_lin_u = (const float*)d_in[17];
    const float* b_lin_u = (const float*)d_in[18];
    const float* w_lin_i = (const float*)d_in[19];
    const float* b_lin_i = (const float*)d_in[20];
    float* out = (float*)d_out;

    float* ws = (float*)d_ws;
    float* user0 = ws;
    float* item0 = user0 + (size_t)NU * HID;
    float* user1 = item0 + (size_t)NI * HID;
    float* item1 = user1 + (size_t)NU * HID;
    float* scratch = item1 + (size_t)NI * HID;  // NU*HID floats; mean buf, later z_user|z_item
    char* after = (char*)(scratch + (size_t)NU * HID);

    const size_t csr_bytes = (size_t)(NI + NU + 2 * NE) * sizeof(int);
    const size_t base_bytes = (size_t)(5 * (size_t)NU * HID) * sizeof(float);
    const bool use_csr = ws_size >= base_bytes + csr_bytes;

    if (use_csr) {
        int* cnt_i = (int*)after;           // NI: cnt -> rowptr -> endptr
        int* cnt_u = cnt_i + NI;            // NU
        int* csr_ui = cnt_u + NU;           // NE src(user) indices sorted by dst(item)
        int* csr_iu = csr_ui + NE;          // NE src(item) indices sorted by dst(user)

        hipMemsetAsync(cnt_i, 0, (size_t)(NI + NU) * sizeof(int), stream);
        hist_kernel<<<(NE + 255) / 256, 256, 0, stream>>>(edge_ui + NE, cnt_i, NE);
        hist_kernel<<<(NE + 255) / 256, 256, 0, stream>>>(edge_iu + NE, cnt_u, NE);
        scan_kernel<<<1, 1024, 0, stream>>>(cnt_i, NI);
        scan_kernel<<<1, 1024, 0, stream>>>(cnt_u, NU);
        fill_kernel<<<(NE + 255) / 256, 256, 0, stream>>>(edge_ui, edge_ui + NE, cnt_i, csr_ui, NE);
        fill_kernel<<<(NE + 255) / 256, 256, 0, stream>>>(edge_iu, edge_iu + NE, cnt_u, csr_iu, NE);
        // cnt_* now hold row END offsets.

        // layer 0
        agg_mean<DIN><<<(NI + 3) / 4, 256, 0, stream>>>(cnt_i, csr_ui, x_user, scratch, NI);
        gemm_fused<<<dim3(HID / 64, (NI + 63) / 64), 256, 0, stream>>>(
            scratch, nullptr, w_msg_ui0, DIN, x_item, w_root_ui0, DIN, b_ui0, item0, NI, HID);
        agg_mean<DIN><<<(NU + 3) / 4, 256, 0, stream>>>(cnt_u, csr_iu, x_item, scratch, NU);
        gemm_fused<<<dim3(HID / 64, (NU + 63) / 64), 256, 0, stream>>>(
            scratch, nullptr, w_msg_iu0, DIN, x_user, w_root_iu0, DIN, b_iu0, user0, NU, HID);
        // layer 1
        agg_mean<HID><<<(NI + 3) / 4, 256, 0, stream>>>(cnt_i, csr_ui, user0, scratch, NI);
        gemm_fused<<<dim3(HID / 64, (NI + 63) / 64), 256, 0, stream>>>(
            scratch, nullptr, w_msg_ui1, HID, item0, w_root_ui1, HID, b_ui1, item1, NI, HID);
        agg_mean<HID><<<(NU + 3) / 4, 256, 0, stream>>>(cnt_u, csr_iu, item0, scratch, NU);
        gemm_fused<<<dim3(HID / 64, (NU + 63) / 64), 256, 0, stream>>>(
            scratch, nullptr, w_msg_iu1, HID, user0, w_root_iu1, HID, b_iu1, user1, NU, HID);
    } else {
        // fallback: proven atomic-scatter path (round 1)
        float* deg_u = (float*)after;
        float* deg_i = deg_u + NU;
        hipMemsetAsync(deg_u, 0, (size_t)(NU + NI) * sizeof(float), stream);
        degree_kernel<<<(NE + 255) / 256, 256, 0, stream>>>(edge_ui + NE, deg_i, NE);
        degree_kernel<<<(NE + 255) / 256, 256, 0, stream>>>(edge_iu + NE, deg_u, NE);

        hipMemsetAsync(scratch, 0, (size_t)NI * DIN * sizeof(float), stream);
        scatter_kernel<DIN><<<(NE * (DIN / 4) + 255) / 256, 256, 0, stream>>>(
            edge_ui, edge_ui + NE, x_user, scratch, NE);
        gemm_fused<<<dim3(HID / 64, (NI + 63) / 64), 256, 0, stream>>>(
            scratch, deg_i, w_msg_ui0, DIN, x_item, w_root_ui0, DIN, b_ui0, item0, NI, HID);

        hipMemsetAsync(scratch, 0, (size_t)NU * DIN * sizeof(float), stream);
        scatter_kernel<DIN><<<(NE * (DIN / 4) + 255) / 256, 256, 0, stream>>>(
            edge_iu, edge_iu + NE, x_item, scratch, NE);
        gemm_fused<<<dim3(HID / 64, (NU + 63) / 64), 256, 0, stream>>>(
            scratch, deg_u, w_msg_iu0, DIN, x_user, w_root_iu0, DIN, b_iu0, user0, NU, HID);

        hipMemsetAsync(scratch, 0, (size_t)NI * HID * sizeof(float), stream);
        scatter_kernel<HID><<<(NE * (HID / 4) + 255) / 256, 256, 0, stream>>>(
            edge_ui, edge_ui + NE, user0, scratch, NE);
        gemm_fused<<<dim3(HID / 64, (NI + 63) / 64), 256, 0, stream>>>(
            scratch, deg_i, w_msg_ui1, HID, item0, w_root_ui1, HID, b_ui1, item1, NI, HID);

        hipMemsetAsync(scratch, 0, (size_t)NU * HID * sizeof(float), stream);
        scatter_kernel<HID><<<(NE * (HID / 4) + 255) / 256, 256, 0, stream>>>(
            edge_iu, edge_iu + NE, item0, scratch, NE);
        gemm_fused<<<dim3(HID / 64, (NU + 63) / 64), 256, 0, stream>>>(
            scratch, deg_u, w_msg_iu1, HID, user0, w_root_iu1, HID, b_iu1, user1, NU, HID);
    }

    // JK concat + per-type linear (scratch reused as z_user | z_item)
    float* z_user = scratch;
    float* z_item = scratch + (size_t)NU * DOUT;
    gemm_fused<<<dim3(DOUT / 64, (NU + 63) / 64), 256, 0, stream>>>(
        user0, nullptr, w_lin_u, HID, user1, w_lin_u + (size_t)HID * DOUT, HID, b_lin_u,
        z_user, NU, DOUT);
    gemm_fused<<<dim3(DOUT / 64, (NI + 63) / 64), 256, 0, stream>>>(
        item0, nullptr, w_lin_i, HID, item1, w_lin_i + (size_t)HID * DOUT, HID, b_lin_i,
        z_item, NI, DOUT);

    decode_kernel<<<((size_t)NLBL * 64 + 255) / 256, 256, 0, stream>>>(
        edge_lbl, z_user, z_item, out, NLBL);
}

// Round 3
// 817.050 us; speedup vs baseline: 11.0977x; 1.8982x over previous
//
#include <hip/hip_runtime.h>

#define NU 50000
#define NI 50000
#define NE 800000
#define NLBL 200000
#define DIN 128
#define HID 256
#define DOUT 128

typedef unsigned short ushort_t;
typedef __attribute__((ext_vector_type(8))) short bf16x8;
typedef __attribute__((ext_vector_type(4))) float f32x4;

__device__ __forceinline__ float bf2f(ushort_t u) {
    union { unsigned int i; float f; } v;
    v.i = ((unsigned int)u) << 16;
    return v.f;
}
__device__ __forceinline__ ushort_t f2bf(float f) {
    union { float f; unsigned int i; } v;
    v.f = f;
    unsigned int r = (v.i + 0x7FFFu + ((v.i >> 16) & 1u)) >> 16;
    return (ushort_t)r;
}
__device__ __forceinline__ void load_lds16(const ushort_t* g, ushort_t* s) {
    __builtin_amdgcn_global_load_lds(
        (const __attribute__((address_space(1))) void*)g,
        (__attribute__((address_space(3))) void*)s, 16, 0, 0);
}

// ================= CSR build =================
__global__ void hist_kernel(const int* __restrict__ dst, int* __restrict__ cnt, int n) {
    int i = blockIdx.x * blockDim.x + threadIdx.x;
    if (i < n) atomicAdd(&cnt[dst[i]], 1);
}

__global__ __launch_bounds__(1024) void scan_kernel(int* __restrict__ data, int n) {
    __shared__ int part[16];
    __shared__ int tot_sh;
    const int tid = threadIdx.x;
    const int lane = tid & 63;
    const int wv = tid >> 6;
    int cv = 0;
    for (int base = 0; base < n; base += 1024) {
        int i = base + tid;
        int v0 = (i < n) ? data[i] : 0;
        int v = v0;
#pragma unroll
        for (int off = 1; off < 64; off <<= 1) {
            int t = __shfl_up(v, off, 64);
            if (lane >= off) v += t;
        }
        if (lane == 63) part[wv] = v;
        __syncthreads();
        if (tid < 16) {
            int p = part[tid];
            int q = p;
#pragma unroll
            for (int off = 1; off < 16; off <<= 1) {
                int t = __shfl_up(q, off, 16);
                if (tid >= off) q += t;
            }
            part[tid] = q - p;
            if (tid == 15) tot_sh = q;
        }
        __syncthreads();
        if (i < n) data[i] = v - v0 + part[wv] + cv;
        cv += tot_sh;
        __syncthreads();
    }
}

__global__ void fill_kernel(const int* __restrict__ src, const int* __restrict__ dst,
                            int* __restrict__ rowpos, int* __restrict__ csr, int n) {
    int e = blockIdx.x * blockDim.x + threadIdx.x;
    if (e < n) {
        int p = atomicAdd(&rowpos[dst[e]], 1);
        csr[p] = src[e];
    }
}

// ================= conversions =================
// fp32 -> bf16, n % 4 == 0
__global__ void cvt_f32_bf16(const float* __restrict__ in, ushort_t* __restrict__ out, int n4) {
    int i = blockIdx.x * blockDim.x + threadIdx.x;
    if (i < n4) {
        float4 v = ((const float4*)in)[i];
        uint2 o;
        o.x = (unsigned int)f2bf(v.x) | ((unsigned int)f2bf(v.y) << 16);
        o.y = (unsigned int)f2bf(v.z) | ((unsigned int)f2bf(v.w) << 16);
        ((uint2*)out)[i] = o;
    }
}

// transpose+convert: W [K][N] f32 -> T [N][K] bf16, batched
struct TJob { const float* W; ushort_t* T; int K; int N; };
struct TJobs { TJob j[12]; };
__global__ void transpose_all(TJobs js) {
    TJob jb = js.j[blockIdx.y];
    int t = blockIdx.x * blockDim.x + threadIdx.x;
    if (t < jb.K * jb.N) {
        int k = t / jb.N, n = t - k * jb.N;
        jb.T[(size_t)n * jb.K + k] = f2bf(jb.W[t]);
    }
}

// ================= gather mean aggregation (bf16 in/out, fp32 accum) =================
// one wave per dst node; endptr[i]=row end, start=endptr[i-1]
template <int D>
__global__ __launch_bounds__(256) void agg_mean_bf(const int* __restrict__ endptr,
                                                   const int* __restrict__ csr,
                                                   const ushort_t* __restrict__ x,
                                                   ushort_t* __restrict__ out, int n) {
    int w = (int)((blockIdx.x * (unsigned)blockDim.x + threadIdx.x) >> 6);
    int lane = threadIdx.x & 63;
    if (w >= n) return;
    int s0 = (w == 0) ? 0 : endptr[w - 1];
    int s1 = endptr[w];
    float sc = (s1 > s0) ? 1.0f / (float)(s1 - s0) : 0.0f;
    if constexpr (D == 128) {
        // row = 64 uints; lane loads 1 uint (2 bf16)
        const unsigned int* xp = (const unsigned int*)x;
        float a0 = 0.f, a1 = 0.f, b0 = 0.f, b1 = 0.f;
        int e = s0;
        for (; e + 1 < s1; e += 2) {
            int iA = __builtin_amdgcn_readfirstlane(csr[e]);
            int iB = __builtin_amdgcn_readfirstlane(csr[e + 1]);
            unsigned int vA = xp[(size_t)iA * 64 + lane];
            unsigned int vB = xp[(size_t)iB * 64 + lane];
            a0 += bf2f((ushort_t)(vA & 0xffff)); a1 += bf2f((ushort_t)(vA >> 16));
            b0 += bf2f((ushort_t)(vB & 0xffff)); b1 += bf2f((ushort_t)(vB >> 16));
        }
        if (e < s1) {
            int iA = __builtin_amdgcn_readfirstlane(csr[e]);
            unsigned int vA = xp[(size_t)iA * 64 + lane];
            a0 += bf2f((ushort_t)(vA & 0xffff)); a1 += bf2f((ushort_t)(vA >> 16));
        }
        unsigned int o = (unsigned int)f2bf((a0 + b0) * sc) |
                         ((unsigned int)f2bf((a1 + b1) * sc) << 16);
        ((unsigned int*)out)[(size_t)w * 64 + lane] = o;
    } else {
        // D == 256: row = 64 uint2; lane loads 1 uint2 (4 bf16)
        const uint2* xp = (const uint2*)x;
        float a[4] = {0.f, 0.f, 0.f, 0.f}, b[4] = {0.f, 0.f, 0.f, 0.f};
        int e = s0;
        for (; e + 1 < s1; e += 2) {
            int iA = __builtin_amdgcn_readfirstlane(csr[e]);
            int iB = __builtin_amdgcn_readfirstlane(csr[e + 1]);
            uint2 vA = xp[(size_t)iA * 64 + lane];
            uint2 vB = xp[(size_t)iB * 64 + lane];
            a[0] += bf2f((ushort_t)(vA.x & 0xffff)); a[1] += bf2f((ushort_t)(vA.x >> 16));
            a[2] += bf2f((ushort_t)(vA.y & 0xffff)); a[3] += bf2f((ushort_t)(vA.y >> 16));
            b[0] += bf2f((ushort_t)(vB.x & 0xffff)); b[1] += bf2f((ushort_t)(vB.x >> 16));
            b[2] += bf2f((ushort_t)(vB.y & 0xffff)); b[3] += bf2f((ushort_t)(vB.y >> 16));
        }
        if (e < s1) {
            int iA = __builtin_amdgcn_readfirstlane(csr[e]);
            uint2 vA = xp[(size_t)iA * 64 + lane];
            a[0] += bf2f((ushort_t)(vA.x & 0xffff)); a[1] += bf2f((ushort_t)(vA.x >> 16));
            a[2] += bf2f((ushort_t)(vA.y & 0xffff)); a[3] += bf2f((ushort_t)(vA.y >> 16));
        }
        uint2 o;
        o.x = (unsigned int)f2bf((a[0] + b[0]) * sc) |
              ((unsigned int)f2bf((a[1] + b[1]) * sc) << 16);
        o.y = (unsigned int)f2bf((a[2] + b[2]) * sc) |
              ((unsigned int)f2bf((a[3] + b[3]) * sc) << 16);
        ((uint2*)out)[(size_t)w * 64 + lane] = o;
    }
}

// ================= MFMA GEMM: C = A1@W1 + A2@W2 + bias =================
// A row-major [M,K] bf16; W*T row-major [N,K] bf16 (pre-transposed); C [M,N] OutT.
// Tile 128x128, BK=32, 4 waves (2x2), each wave 4x4 frags of 16x16x32.
// N % 128 == 0, K % 32 == 0.
template <typename OutT>
__global__ __launch_bounds__(256) void gemm_mfma(
    const ushort_t* __restrict__ A1, const ushort_t* __restrict__ W1T, int K1,
    const ushort_t* __restrict__ A2, const ushort_t* __restrict__ W2T, int K2,
    const float* __restrict__ bias, OutT* __restrict__ C, int M, int N) {
    __shared__ ushort_t sA[128 * 32];
    __shared__ ushort_t sB[128 * 32];
    const int tid = threadIdx.x;
    const int lane = tid & 63;
    const int wv = tid >> 6;
    const int wm = wv & 1, wn = wv >> 1;
    const int bm = blockIdx.y * 128, bn = blockIdx.x * 128;

    f32x4 acc[4][4] = {};

    const int srow = tid >> 2;           // 0..63
    const int scol = (tid & 3) * 8;      // element offset (8 bf16 = 16B)

    for (int part = 0; part < 2; ++part) {
        const ushort_t* A = part ? A2 : A1;
        const ushort_t* WT = part ? W2T : W1T;
        const int K = part ? K2 : K1;
        int ar0 = bm + srow;       if (ar0 > M - 1) ar0 = M - 1;
        int ar1 = bm + 64 + srow;  if (ar1 > M - 1) ar1 = M - 1;
        const size_t aoff0 = (size_t)ar0 * K + scol;
        const size_t aoff1 = (size_t)ar1 * K + scol;
        const size_t boff0 = (size_t)(bn + srow) * K + scol;
        const size_t boff1 = (size_t)(bn + 64 + srow) * K + scol;
        for (int k0 = 0; k0 < K; k0 += 32) {
            __syncthreads();
            load_lds16(A + aoff0 + k0, sA + tid * 8);
            load_lds16(A + aoff1 + k0, sA + 2048 + tid * 8);
            load_lds16(WT + boff0 + k0, sB + tid * 8);
            load_lds16(WT + boff1 + k0, sB + 2048 + tid * 8);
            __syncthreads();
            const ushort_t* pA = sA + ((wm * 64 + (lane & 15)) * 32 + (lane >> 4) * 8);
            const ushort_t* pB = sB + ((wn * 64 + (lane & 15)) * 32 + (lane >> 4) * 8);
            bf16x8 af[4], bf[4];
#pragma unroll
            for (int mt = 0; mt < 4; ++mt) af[mt] = *(const bf16x8*)(pA + mt * 512);
#pragma unroll
            for (int nt = 0; nt < 4; ++nt) bf[nt] = *(const bf16x8*)(pB + nt * 512);
#pragma unroll
            for (int mt = 0; mt < 4; ++mt)
#pragma unroll
                for (int nt = 0; nt < 4; ++nt)
                    acc[mt][nt] = __builtin_amdgcn_mfma_f32_16x16x32_bf16(
                        af[mt], bf[nt], acc[mt][nt], 0, 0, 0);
        }
    }

    // epilogue: C/D layout col=lane&15, row=(lane>>4)*4+reg
#pragma unroll
    for (int mt = 0; mt < 4; ++mt) {
#pragma unroll
        for (int r = 0; r < 4; ++r) {
            int row = bm + wm * 64 + mt * 16 + (lane >> 4) * 4 + r;
            if (row >= M) continue;
#pragma unroll
            for (int nt = 0; nt < 4; ++nt) {
                int col = bn + wn * 64 + nt * 16 + (lane & 15);
                float v = acc[mt][nt][r] + bias[col];
                if constexpr (sizeof(OutT) == 2)
                    ((ushort_t*)C)[(size_t)row * N + col] = f2bf(v);
                else
                    ((float*)C)[(size_t)row * N + col] = v;
            }
        }
    }
}

// ================= decode =================
__global__ void decode_kernel(const int* __restrict__ lbl, const float* __restrict__ zu,
                              const float* __restrict__ zi, float* __restrict__ out, int n) {
    int gid = blockIdx.x * blockDim.x + threadIdx.x;
    int e = gid >> 6;
    int lane = gid & 63;
    if (e >= n) return;
    int u = lbl[e];
    int it = lbl[n + e];
    const float2 a = *(const float2*)(zu + (size_t)u * DOUT + lane * 2);
    const float2 b = *(const float2*)(zi + (size_t)it * DOUT + lane * 2);
    float s = a.x * b.x + a.y * b.y;
#pragma unroll
    for (int off = 32; off > 0; off >>= 1) s += __shfl_down(s, off, 64);
    if (lane == 0) out[e] = s;
}

extern "C" void kernel_launch(void* const* d_in, const int* in_sizes, int n_in,
                              void* d_out, int out_size, void* d_ws, size_t ws_size,
                              hipStream_t stream) {
    const float* x_user = (const float*)d_in[0];
    const float* x_item = (const float*)d_in[1];
    const int* edge_ui = (const int*)d_in[2];   // row0=src(user), row1=dst(item)
    const int* edge_iu = (const int*)d_in[3];   // row0=src(item), row1=dst(user)
    const int* edge_lbl = (const int*)d_in[4];
    const float* w_msg_ui0 = (const float*)d_in[5];
    const float* b_ui0 = (const float*)d_in[6];
    const float* w_root_ui0 = (const float*)d_in[7];
    const float* w_msg_iu0 = (const float*)d_in[8];
    const float* b_iu0 = (const float*)d_in[9];
    const float* w_root_iu0 = (const float*)d_in[10];
    const float* w_msg_ui1 = (const float*)d_in[11];
    const float* b_ui1 = (const float*)d_in[12];
    const float* w_root_ui1 = (const float*)d_in[13];
    const float* w_msg_iu1 = (const float*)d_in[14];
    const float* b_iu1 = (const float*)d_in[15];
    const float* w_root_iu1 = (const float*)d_in[16];
    const float* w_lin_u = (const float*)d_in[17];  // [512,128]
    const float* b_lin_u = (const float*)d_in[18];
    const float* w_lin_i = (const float*)d_in[19];
    const float* b_lin_i = (const float*)d_in[20];
    float* out = (float*)d_out;

    // ---- workspace layout (bytes) ----
    char* p = (char*)d_ws;
    ushort_t* user0 = (ushort_t*)p;  p += (size_t)NU * HID * 2;
    ushort_t* item0 = (ushort_t*)p;  p += (size_t)NI * HID * 2;
    ushort_t* user1 = (ushort_t*)p;  p += (size_t)NU * HID * 2;
    ushort_t* item1 = (ushort_t*)p;  p += (size_t)NI * HID * 2;
    ushort_t* mean  = (ushort_t*)p;  p += (size_t)NU * HID * 2;
    ushort_t* xb_u  = (ushort_t*)p;  p += (size_t)NU * DIN * 2;
    ushort_t* xb_i  = (ushort_t*)p;  p += (size_t)NI * DIN * 2;
    float* z_user   = (float*)p;     p += (size_t)NU * DOUT * 4;
    float* z_item   = (float*)p;     p += (size_t)NI * DOUT * 4;
    int* cnt_i      = (int*)p;       p += (size_t)NI * 4;
    int* cnt_u      = (int*)p;       p += (size_t)NU * 4;
    int* csr_ui     = (int*)p;       p += (size_t)NE * 4;
    int* csr_iu     = (int*)p;       p += (size_t)NE * 4;
    // transposed bf16 weights
    ushort_t* T_msg_ui0 = (ushort_t*)p; p += (size_t)DIN * HID * 2;
    ushort_t* T_root_ui0 = (ushort_t*)p; p += (size_t)DIN * HID * 2;
    ushort_t* T_msg_iu0 = (ushort_t*)p; p += (size_t)DIN * HID * 2;
    ushort_t* T_root_iu0 = (ushort_t*)p; p += (size_t)DIN * HID * 2;
    ushort_t* T_msg_ui1 = (ushort_t*)p; p += (size_t)HID * HID * 2;
    ushort_t* T_root_ui1 = (ushort_t*)p; p += (size_t)HID * HID * 2;
    ushort_t* T_msg_iu1 = (ushort_t*)p; p += (size_t)HID * HID * 2;
    ushort_t* T_root_iu1 = (ushort_t*)p; p += (size_t)HID * HID * 2;
    ushort_t* T_lin_u_a = (ushort_t*)p; p += (size_t)HID * DOUT * 2;
    ushort_t* T_lin_u_b = (ushort_t*)p; p += (size_t)HID * DOUT * 2;
    ushort_t* T_lin_i_a = (ushort_t*)p; p += (size_t)HID * DOUT * 2;
    ushort_t* T_lin_i_b = (ushort_t*)p; p += (size_t)HID * DOUT * 2;

    // ---- CSR build ----
    hipMemsetAsync(cnt_i, 0, (size_t)(NI + NU) * sizeof(int), stream);
    hist_kernel<<<(NE + 255) / 256, 256, 0, stream>>>(edge_ui + NE, cnt_i, NE);
    hist_kernel<<<(NE + 255) / 256, 256, 0, stream>>>(edge_iu + NE, cnt_u, NE);
    scan_kernel<<<1, 1024, 0, stream>>>(cnt_i, NI);
    scan_kernel<<<1, 1024, 0, stream>>>(cnt_u, NU);
    fill_kernel<<<(NE + 255) / 256, 256, 0, stream>>>(edge_ui, edge_ui + NE, cnt_i, csr_ui, NE);
    fill_kernel<<<(NE + 255) / 256, 256, 0, stream>>>(edge_iu, edge_iu + NE, cnt_u, csr_iu, NE);
    // cnt_* now hold row END offsets.

    // ---- convert inputs & weights to bf16 ----
    cvt_f32_bf16<<<(NU * DIN / 4 + 255) / 256, 256, 0, stream>>>(x_user, xb_u, NU * DIN / 4);
    cvt_f32_bf16<<<(NI * DIN / 4 + 255) / 256, 256, 0, stream>>>(x_item, xb_i, NI * DIN / 4);
    TJobs jobs = {{
        {w_msg_ui0, T_msg_ui0, DIN, HID}, {w_root_ui0, T_root_ui0, DIN, HID},
        {w_msg_iu0, T_msg_iu0, DIN, HID}, {w_root_iu0, T_root_iu0, DIN, HID},
        {w_msg_ui1, T_msg_ui1, HID, HID}, {w_root_ui1, T_root_ui1, HID, HID},
        {w_msg_iu1, T_msg_iu1, HID, HID}, {w_root_iu1, T_root_iu1, HID, HID},
        {w_lin_u, T_lin_u_a, HID, DOUT}, {w_lin_u + (size_t)HID * DOUT, T_lin_u_b, HID, DOUT},
        {w_lin_i, T_lin_i_a, HID, DOUT}, {w_lin_i + (size_t)HID * DOUT, T_lin_i_b, HID, DOUT},
    }};
    transpose_all<<<dim3((HID * HID + 255) / 256, 12), 256, 0, stream>>>(jobs);

    // ---- layer 0 ----
    agg_mean_bf<DIN><<<(NI + 3) / 4, 256, 0, stream>>>(cnt_i, csr_ui, xb_u, mean, NI);
    gemm_mfma<ushort_t><<<dim3(HID / 128, (NI + 127) / 128), 256, 0, stream>>>(
        mean, T_msg_ui0, DIN, xb_i, T_root_ui0, DIN, b_ui0, item0, NI, HID);
    agg_mean_bf<DIN><<<(NU + 3) / 4, 256, 0, stream>>>(cnt_u, csr_iu, xb_i, mean, NU);
    gemm_mfma<ushort_t><<<dim3(HID / 128, (NU + 127) / 128), 256, 0, stream>>>(
        mean, T_msg_iu0, DIN, xb_u, T_root_iu0, DIN, b_iu0, user0, NU, HID);

    // ---- layer 1 ----
    agg_mean_bf<HID><<<(NI + 3) / 4, 256, 0, stream>>>(cnt_i, csr_ui, user0, mean, NI);
    gemm_mfma<ushort_t><<<dim3(HID / 128, (NI + 127) / 128), 256, 0, stream>>>(
        mean, T_msg_ui1, HID, item0, T_root_ui1, HID, b_ui1, item1, NI, HID);
    agg_mean_bf<HID><<<(NU + 3) / 4, 256, 0, stream>>>(cnt_u, csr_iu, item0, mean, NU);
    gemm_mfma<ushort_t><<<dim3(HID / 128, (NU + 127) / 128), 256, 0, stream>>>(
        mean, T_msg_iu1, HID, user0, T_root_iu1, HID, b_iu1, user1, NU, HID);

    // ---- JK concat + per-type linear (fp32 out) ----
    gemm_mfma<float><<<dim3(DOUT / 128, (NU + 127) / 128), 256, 0, stream>>>(
        user0, T_lin_u_a, HID, user1, T_lin_u_b, HID, b_lin_u, z_user, NU, DOUT);
    gemm_mfma<float><<<dim3(DOUT / 128, (NI + 127) / 128), 256, 0, stream>>>(
        item0, T_lin_i_a, HID, item1, T_lin_i_b, HID, b_lin_i, z_item, NI, DOUT);

    // ---- decode ----
    decode_kernel<<<((size_t)NLBL * 64 + 255) / 256, 256, 0, stream>>>(
        edge_lbl, z_user, z_item, out, NLBL);
}

// Round 4
// 663.811 us; speedup vs baseline: 13.6595x; 1.2308x over previous
//
#include <hip/hip_runtime.h>

#define NU 50000
#define NI 50000
#define NE 800000
#define NLBL 200000
#define DIN 128
#define HID 256
#define DOUT 128

typedef unsigned short ushort_t;
typedef __attribute__((ext_vector_type(8))) short bf16x8;
typedef __attribute__((ext_vector_type(4))) float f32x4;

__device__ __forceinline__ float bf2f(unsigned int u_shifted) {
    union { unsigned int i; float f; } v;
    v.i = u_shifted;
    return v.f;
}
__device__ __forceinline__ float bf_lo(unsigned int u) { return bf2f(u << 16); }
__device__ __forceinline__ float bf_hi(unsigned int u) { return bf2f(u & 0xffff0000u); }
__device__ __forceinline__ ushort_t f2bf(float f) {
    union { float f; unsigned int i; } v;
    v.f = f;
    unsigned int r = (v.i + 0x7FFFu + ((v.i >> 16) & 1u)) >> 16;
    return (ushort_t)r;
}
__device__ __forceinline__ void load_lds16(const ushort_t* g, ushort_t* s) {
    __builtin_amdgcn_global_load_lds(
        (const __attribute__((address_space(1))) void*)g,
        (__attribute__((address_space(3))) void*)s, 16, 0, 0);
}

// ================= CSR build =================
__global__ void hist_kernel(const int* __restrict__ dst, int* __restrict__ cnt, int n) {
    int i = blockIdx.x * blockDim.x + threadIdx.x;
    if (i < n) atomicAdd(&cnt[dst[i]], 1);
}

// ---- 3-phase exclusive scan over n ints (2048 per block) ----
__global__ __launch_bounds__(256) void scan1(const int* __restrict__ d, int* __restrict__ part, int n) {
    __shared__ int wsum[4];
    int b = blockIdx.x, t = threadIdx.x;
    int i0 = b * 2048 + t * 8;
    int s = 0;
#pragma unroll
    for (int k = 0; k < 8; ++k) s += (i0 + k < n) ? d[i0 + k] : 0;
#pragma unroll
    for (int off = 32; off > 0; off >>= 1) s += __shfl_down(s, off, 64);
    if ((t & 63) == 0) wsum[t >> 6] = s;
    __syncthreads();
    if (t == 0) part[b] = wsum[0] + wsum[1] + wsum[2] + wsum[3];
}
__global__ __launch_bounds__(64) void scan2(int* __restrict__ part, int nb) {
    int lane = threadIdx.x;
    int v = (lane < nb) ? part[lane] : 0;
    int incl = v;
#pragma unroll
    for (int off = 1; off < 64; off <<= 1) {
        int t = __shfl_up(incl, off, 64);
        if (lane >= off) incl += t;
    }
    if (lane < nb) part[lane] = incl - v;  // exclusive
}
__global__ __launch_bounds__(256) void scan3(int* __restrict__ d, const int* __restrict__ part, int n) {
    __shared__ int wsum[4];
    int b = blockIdx.x, t = threadIdx.x;
    int lane = t & 63, wv = t >> 6;
    int i0 = b * 2048 + t * 8;
    int v[8];
    int tsum = 0;
#pragma unroll
    for (int k = 0; k < 8; ++k) {
        v[k] = (i0 + k < n) ? d[i0 + k] : 0;
        tsum += v[k];
    }
    int incl = tsum;
#pragma unroll
    for (int off = 1; off < 64; off <<= 1) {
        int tv = __shfl_up(incl, off, 64);
        if (lane >= off) incl += tv;
    }
    if (lane == 63) wsum[wv] = incl;
    __syncthreads();
    int woff = 0;
    for (int w = 0; w < wv; ++w) woff += wsum[w];
    int run = part[b] + woff + (incl - tsum);
#pragma unroll
    for (int k = 0; k < 8; ++k) {
        if (i0 + k < n) d[i0 + k] = run;
        run += v[k];
    }
}

__global__ void fill_kernel(const int* __restrict__ src, const int* __restrict__ dst,
                            int* __restrict__ rowpos, int* __restrict__ csr, int n) {
    int e = blockIdx.x * blockDim.x + threadIdx.x;
    if (e < n) {
        int p = atomicAdd(&rowpos[dst[e]], 1);
        csr[p] = src[e];
    }
}

// ================= conversions =================
__global__ void cvt_f32_bf16(const float* __restrict__ in, ushort_t* __restrict__ out, int n4) {
    int i = blockIdx.x * blockDim.x + threadIdx.x;
    if (i < n4) {
        float4 v = ((const float4*)in)[i];
        uint2 o;
        o.x = (unsigned int)f2bf(v.x) | ((unsigned int)f2bf(v.y) << 16);
        o.y = (unsigned int)f2bf(v.z) | ((unsigned int)f2bf(v.w) << 16);
        ((uint2*)out)[i] = o;
    }
}

struct TJob { const float* W; ushort_t* T; int K; int N; };
struct TJobs { TJob j[12]; };
__global__ void transpose_all(TJobs js) {
    TJob jb = js.j[blockIdx.y];
    int t = blockIdx.x * blockDim.x + threadIdx.x;
    if (t < jb.K * jb.N) {
        int k = t / jb.N, n = t - k * jb.N;
        jb.T[(size_t)n * jb.K + k] = f2bf(jb.W[t]);
    }
}

// ================= gather mean aggregation (bf16, fp32 accum) =================
// one wave per dst node. endptr[w] = row end; start = (w==0) ? s0_first : endptr[w-1].
// Indices for a row are fetched with ONE coalesced load (<=64 at a time) and
// broadcast via shfl; row gathers unrolled 4x for MLP.
template <int D>
__global__ __launch_bounds__(256) void agg_mean_bf(const int* __restrict__ endptr,
                                                   const int* __restrict__ csr,
                                                   const ushort_t* __restrict__ x,
                                                   ushort_t* __restrict__ out, int n,
                                                   int s0_first) {
    int w = (int)((blockIdx.x * (unsigned)blockDim.x + threadIdx.x) >> 6);
    int lane = threadIdx.x & 63;
    if (w >= n) return;
    int s0 = (w == 0) ? s0_first : endptr[w - 1];
    int s1 = endptr[w];
    int cnt = s1 - s0;
    float sc = (cnt > 0) ? 1.0f / (float)cnt : 0.0f;

    if constexpr (D == 256) {
        const uint2* xp = (const uint2*)x;
        float a[4] = {0.f, 0.f, 0.f, 0.f}, b[4] = {0.f, 0.f, 0.f, 0.f};
        for (int chunk = 0; chunk < cnt; chunk += 64) {
            int m = cnt - chunk;
            if (m > 64) m = 64;
            int vidx = csr[s0 + chunk + ((lane < m) ? lane : (m - 1))];
            int j = 0;
            for (; j + 3 < m; j += 4) {
                int i0 = __shfl(vidx, j, 64);
                int i1 = __shfl(vidx, j + 1, 64);
                int i2 = __shfl(vidx, j + 2, 64);
                int i3 = __shfl(vidx, j + 3, 64);
                uint2 v0 = xp[(size_t)i0 * 64 + lane];
                uint2 v1 = xp[(size_t)i1 * 64 + lane];
                uint2 v2 = xp[(size_t)i2 * 64 + lane];
                uint2 v3 = xp[(size_t)i3 * 64 + lane];
                a[0] += bf_lo(v0.x) + bf_lo(v2.x); a[1] += bf_hi(v0.x) + bf_hi(v2.x);
                a[2] += bf_lo(v0.y) + bf_lo(v2.y); a[3] += bf_hi(v0.y) + bf_hi(v2.y);
                b[0] += bf_lo(v1.x) + bf_lo(v3.x); b[1] += bf_hi(v1.x) + bf_hi(v3.x);
                b[2] += bf_lo(v1.y) + bf_lo(v3.y); b[3] += bf_hi(v1.y) + bf_hi(v3.y);
            }
            for (; j < m; ++j) {
                int i0 = __shfl(vidx, j, 64);
                uint2 v0 = xp[(size_t)i0 * 64 + lane];
                a[0] += bf_lo(v0.x); a[1] += bf_hi(v0.x);
                a[2] += bf_lo(v0.y); a[3] += bf_hi(v0.y);
            }
        }
        uint2 o;
        o.x = (unsigned int)f2bf((a[0] + b[0]) * sc) |
              ((unsigned int)f2bf((a[1] + b[1]) * sc) << 16);
        o.y = (unsigned int)f2bf((a[2] + b[2]) * sc) |
              ((unsigned int)f2bf((a[3] + b[3]) * sc) << 16);
        ((uint2*)out)[(size_t)w * 64 + lane] = o;
    } else {
        // D == 128: row = 64 uints, lane loads 1 uint
        const unsigned int* xp = (const unsigned int*)x;
        float a0 = 0.f, a1 = 0.f, b0 = 0.f, b1 = 0.f;
        for (int chunk = 0; chunk < cnt; chunk += 64) {
            int m = cnt - chunk;
            if (m > 64) m = 64;
            int vidx = csr[s0 + chunk + ((lane < m) ? lane : (m - 1))];
            int j = 0;
            for (; j + 3 < m; j += 4) {
                int i0 = __shfl(vidx, j, 64);
                int i1 = __shfl(vidx, j + 1, 64);
                int i2 = __shfl(vidx, j + 2, 64);
                int i3 = __shfl(vidx, j + 3, 64);
                unsigned int v0 = xp[(size_t)i0 * 64 + lane];
                unsigned int v1 = xp[(size_t)i1 * 64 + lane];
                unsigned int v2 = xp[(size_t)i2 * 64 + lane];
                unsigned int v3 = xp[(size_t)i3 * 64 + lane];
                a0 += bf_lo(v0) + bf_lo(v2); a1 += bf_hi(v0) + bf_hi(v2);
                b0 += bf_lo(v1) + bf_lo(v3); b1 += bf_hi(v1) + bf_hi(v3);
            }
            for (; j < m; ++j) {
                int i0 = __shfl(vidx, j, 64);
                unsigned int v0 = xp[(size_t)i0 * 64 + lane];
                a0 += bf_lo(v0); a1 += bf_hi(v0);
            }
        }
        unsigned int o = (unsigned int)f2bf((a0 + b0) * sc) |
                         ((unsigned int)f2bf((a1 + b1) * sc) << 16);
        ((unsigned int*)out)[(size_t)w * 64 + lane] = o;
    }
}

// ================= MFMA GEMM: C = A1@W1 + A2@W2 + bias =================
// A [M,K] bf16 row-major; W*T [N,K] bf16 (pre-transposed); C [M,N] OutT.
// Tile 128x128, BK=32, 4 waves, each 4x4 frags of 16x16x32.
template <typename OutT>
__global__ __launch_bounds__(256) void gemm_mfma(
    const ushort_t* __restrict__ A1, const ushort_t* __restrict__ W1T, int K1,
    const ushort_t* __restrict__ A2, const ushort_t* __restrict__ W2T, int K2,
    const float* __restrict__ bias, OutT* __restrict__ C, int M, int N) {
    __shared__ ushort_t sA[128 * 32];
    __shared__ ushort_t sB[128 * 32];
    const int tid = threadIdx.x;
    const int lane = tid & 63;
    const int wv = tid >> 6;
    const int wm = wv & 1, wn = wv >> 1;
    const int bm = blockIdx.y * 128, bn = blockIdx.x * 128;

    f32x4 acc[4][4] = {};

    const int srow = tid >> 2;
    const int scol = (tid & 3) * 8;

    for (int part = 0; part < 2; ++part) {
        const ushort_t* A = part ? A2 : A1;
        const ushort_t* WT = part ? W2T : W1T;
        const int K = part ? K2 : K1;
        int ar0 = bm + srow;       if (ar0 > M - 1) ar0 = M - 1;
        int ar1 = bm + 64 + srow;  if (ar1 > M - 1) ar1 = M - 1;
        const size_t aoff0 = (size_t)ar0 * K + scol;
        const size_t aoff1 = (size_t)ar1 * K + scol;
        const size_t boff0 = (size_t)(bn + srow) * K + scol;
        const size_t boff1 = (size_t)(bn + 64 + srow) * K + scol;
        for (int k0 = 0; k0 < K; k0 += 32) {
            __syncthreads();
            load_lds16(A + aoff0 + k0, sA + tid * 8);
            load_lds16(A + aoff1 + k0, sA + 2048 + tid * 8);
            load_lds16(WT + boff0 + k0, sB + tid * 8);
            load_lds16(WT + boff1 + k0, sB + 2048 + tid * 8);
            __syncthreads();
            const ushort_t* pA = sA + ((wm * 64 + (lane & 15)) * 32 + (lane >> 4) * 8);
            const ushort_t* pB = sB + ((wn * 64 + (lane & 15)) * 32 + (lane >> 4) * 8);
            bf16x8 af[4], bfr[4];
#pragma unroll
            for (int mt = 0; mt < 4; ++mt) af[mt] = *(const bf16x8*)(pA + mt * 512);
#pragma unroll
            for (int nt = 0; nt < 4; ++nt) bfr[nt] = *(const bf16x8*)(pB + nt * 512);
#pragma unroll
            for (int mt = 0; mt < 4; ++mt)
#pragma unroll
                for (int nt = 0; nt < 4; ++nt)
                    acc[mt][nt] = __builtin_amdgcn_mfma_f32_16x16x32_bf16(
                        af[mt], bfr[nt], acc[mt][nt], 0, 0, 0);
        }
    }

#pragma unroll
    for (int mt = 0; mt < 4; ++mt) {
#pragma unroll
        for (int r = 0; r < 4; ++r) {
            int row = bm + wm * 64 + mt * 16 + (lane >> 4) * 4 + r;
            if (row >= M) continue;
#pragma unroll
            for (int nt = 0; nt < 4; ++nt) {
                int col = bn + wn * 64 + nt * 16 + (lane & 15);
                float v = acc[mt][nt][r] + bias[col];
                if constexpr (sizeof(OutT) == 2)
                    ((ushort_t*)C)[(size_t)row * N + col] = f2bf(v);
                else
                    ((float*)C)[(size_t)row * N + col] = v;
            }
        }
    }
}

// ================= decode: bf16 z, 2 edges per wave (32-lane halves) =================
__global__ void decode_kernel(const int* __restrict__ lbl, const ushort_t* __restrict__ zu,
                              const ushort_t* __restrict__ zi, float* __restrict__ out, int n) {
    int gid = blockIdx.x * blockDim.x + threadIdx.x;
    int wave = gid >> 6;
    int lane = threadIdx.x & 63;
    int half = lane >> 5;
    int l = lane & 31;
    int e = wave * 2 + half;
    if (e >= n) return;
    int u = lbl[e];
    int it = lbl[n + e];
    // row = 128 bf16 = 32 x uint2
    uint2 a = ((const uint2*)zu)[(size_t)u * 32 + l];
    uint2 b = ((const uint2*)zi)[(size_t)it * 32 + l];
    float s = bf_lo(a.x) * bf_lo(b.x) + bf_hi(a.x) * bf_hi(b.x) +
              bf_lo(a.y) * bf_lo(b.y) + bf_hi(a.y) * bf_hi(b.y);
#pragma unroll
    for (int off = 16; off > 0; off >>= 1) s += __shfl_down(s, off, 32);
    if (l == 0) out[e] = s;
}

extern "C" void kernel_launch(void* const* d_in, const int* in_sizes, int n_in,
                              void* d_out, int out_size, void* d_ws, size_t ws_size,
                              hipStream_t stream) {
    const float* x_user = (const float*)d_in[0];
    const float* x_item = (const float*)d_in[1];
    const int* edge_ui = (const int*)d_in[2];   // row0=src(user), row1=dst(item)
    const int* edge_iu = (const int*)d_in[3];   // row0=src(item), row1=dst(user)
    const int* edge_lbl = (const int*)d_in[4];
    const float* w_msg_ui0 = (const float*)d_in[5];
    const float* b_ui0 = (const float*)d_in[6];
    const float* w_root_ui0 = (const float*)d_in[7];
    const float* w_msg_iu0 = (const float*)d_in[8];
    const float* b_iu0 = (const float*)d_in[9];
    const float* w_root_iu0 = (const float*)d_in[10];
    const float* w_msg_ui1 = (const float*)d_in[11];
    const float* b_ui1 = (const float*)d_in[12];
    const float* w_root_ui1 = (const float*)d_in[13];
    const float* w_msg_iu1 = (const float*)d_in[14];
    const float* b_iu1 = (const float*)d_in[15];
    const float* w_root_iu1 = (const float*)d_in[16];
    const float* w_lin_u = (const float*)d_in[17];  // [512,128]
    const float* b_lin_u = (const float*)d_in[18];
    const float* w_lin_i = (const float*)d_in[19];
    const float* b_lin_i = (const float*)d_in[20];
    float* out = (float*)d_out;

    // ---- workspace layout ----
    char* p = (char*)d_ws;
    ushort_t* user0 = (ushort_t*)p;  p += (size_t)NU * HID * 2;
    ushort_t* item0 = (ushort_t*)p;  p += (size_t)NI * HID * 2;
    ushort_t* user1 = (ushort_t*)p;  p += (size_t)NU * HID * 2;
    ushort_t* item1 = (ushort_t*)p;  p += (size_t)NI * HID * 2;
    ushort_t* mean  = (ushort_t*)p;  p += (size_t)NU * HID * 2;
    ushort_t* xb_u  = (ushort_t*)p;  p += (size_t)NU * DIN * 2;
    ushort_t* xb_i  = (ushort_t*)p;  p += (size_t)NI * DIN * 2;
    ushort_t* z_user = (ushort_t*)p; p += (size_t)NU * DOUT * 2;
    ushort_t* z_item = (ushort_t*)p; p += (size_t)NI * DOUT * 2;
    int* cnt_i      = (int*)p;       p += (size_t)NI * 4;
    int* cnt_u      = (int*)p;       p += (size_t)NU * 4;   // contiguous after cnt_i
    int* csr        = (int*)p;       p += (size_t)2 * NE * 4;  // [0,NE): ui; [NE,2NE): iu
    int* scan_part  = (int*)p;       p += 64 * 4;
    ushort_t* T_msg_ui0 = (ushort_t*)p; p += (size_t)DIN * HID * 2;
    ushort_t* T_root_ui0 = (ushort_t*)p; p += (size_t)DIN * HID * 2;
    ushort_t* T_msg_iu0 = (ushort_t*)p; p += (size_t)DIN * HID * 2;
    ushort_t* T_root_iu0 = (ushort_t*)p; p += (size_t)DIN * HID * 2;
    ushort_t* T_msg_ui1 = (ushort_t*)p; p += (size_t)HID * HID * 2;
    ushort_t* T_root_ui1 = (ushort_t*)p; p += (size_t)HID * HID * 2;
    ushort_t* T_msg_iu1 = (ushort_t*)p; p += (size_t)HID * HID * 2;
    ushort_t* T_root_iu1 = (ushort_t*)p; p += (size_t)HID * HID * 2;
    ushort_t* T_lin_u_a = (ushort_t*)p; p += (size_t)HID * DOUT * 2;
    ushort_t* T_lin_u_b = (ushort_t*)p; p += (size_t)HID * DOUT * 2;
    ushort_t* T_lin_i_a = (ushort_t*)p; p += (size_t)HID * DOUT * 2;
    ushort_t* T_lin_i_b = (ushort_t*)p; p += (size_t)HID * DOUT * 2;

    // ---- CSR build: hist -> concatenated exclusive scan -> fill ----
    const int NCNT = NI + NU;
    const int NB = (NCNT + 2047) / 2048;
    hipMemsetAsync(cnt_i, 0, (size_t)NCNT * sizeof(int), stream);
    hist_kernel<<<(NE + 255) / 256, 256, 0, stream>>>(edge_ui + NE, cnt_i, NE);
    hist_kernel<<<(NE + 255) / 256, 256, 0, stream>>>(edge_iu + NE, cnt_u, NE);
    scan1<<<NB, 256, 0, stream>>>(cnt_i, scan_part, NCNT);
    scan2<<<1, 64, 0, stream>>>(scan_part, NB);
    scan3<<<NB, 256, 0, stream>>>(cnt_i, scan_part, NCNT);
    fill_kernel<<<(NE + 255) / 256, 256, 0, stream>>>(edge_ui, edge_ui + NE, cnt_i, csr, NE);
    fill_kernel<<<(NE + 255) / 256, 256, 0, stream>>>(edge_iu, edge_iu + NE, cnt_u, csr, NE);
    // cnt_i/cnt_u now hold absolute row END offsets into csr.

    // ---- convert inputs & weights to bf16 ----
    cvt_f32_bf16<<<(NU * DIN / 4 + 255) / 256, 256, 0, stream>>>(x_user, xb_u, NU * DIN / 4);
    cvt_f32_bf16<<<(NI * DIN / 4 + 255) / 256, 256, 0, stream>>>(x_item, xb_i, NI * DIN / 4);
    TJobs jobs = {{
        {w_msg_ui0, T_msg_ui0, DIN, HID}, {w_root_ui0, T_root_ui0, DIN, HID},
        {w_msg_iu0, T_msg_iu0, DIN, HID}, {w_root_iu0, T_root_iu0, DIN, HID},
        {w_msg_ui1, T_msg_ui1, HID, HID}, {w_root_ui1, T_root_ui1, HID, HID},
        {w_msg_iu1, T_msg_iu1, HID, HID}, {w_root_iu1, T_root_iu1, HID, HID},
        {w_lin_u, T_lin_u_a, HID, DOUT}, {w_lin_u + (size_t)HID * DOUT, T_lin_u_b, HID, DOUT},
        {w_lin_i, T_lin_i_a, HID, DOUT}, {w_lin_i + (size_t)HID * DOUT, T_lin_i_b, HID, DOUT},
    }};
    transpose_all<<<dim3((HID * HID + 255) / 256, 12), 256, 0, stream>>>(jobs);

    // ---- layer 0 ----
    agg_mean_bf<DIN><<<(NI + 3) / 4, 256, 0, stream>>>(cnt_i, csr, xb_u, mean, NI, 0);
    gemm_mfma<ushort_t><<<dim3(HID / 128, (NI + 127) / 128), 256, 0, stream>>>(
        mean, T_msg_ui0, DIN, xb_i, T_root_ui0, DIN, b_ui0, item0, NI, HID);
    agg_mean_bf<DIN><<<(NU + 3) / 4, 256, 0, stream>>>(cnt_u, csr, xb_i, mean, NU, NE);
    gemm_mfma<ushort_t><<<dim3(HID / 128, (NU + 127) / 128), 256, 0, stream>>>(
        mean, T_msg_iu0, DIN, xb_u, T_root_iu0, DIN, b_iu0, user0, NU, HID);

    // ---- layer 1 ----
    agg_mean_bf<HID><<<(NI + 3) / 4, 256, 0, stream>>>(cnt_i, csr, user0, mean, NI, 0);
    gemm_mfma<ushort_t><<<dim3(HID / 128, (NI + 127) / 128), 256, 0, stream>>>(
        mean, T_msg_ui1, HID, item0, T_root_ui1, HID, b_ui1, item1, NI, HID);
    agg_mean_bf<HID><<<(NU + 3) / 4, 256, 0, stream>>>(cnt_u, csr, item0, mean, NU, NE);
    gemm_mfma<ushort_t><<<dim3(HID / 128, (NU + 127) / 128), 256, 0, stream>>>(
        mean, T_msg_iu1, HID, user0, T_root_iu1, HID, b_iu1, user1, NU, HID);

    // ---- JK concat + per-type linear (bf16 out) ----
    gemm_mfma<ushort_t><<<dim3(DOUT / 128, (NU + 127) / 128), 256, 0, stream>>>(
        user0, T_lin_u_a, HID, user1, T_lin_u_b, HID, b_lin_u, z_user, NU, DOUT);
    gemm_mfma<ushort_t><<<dim3(DOUT / 128, (NI + 127) / 128), 256, 0, stream>>>(
        item0, T_lin_i_a, HID, item1, T_lin_i_b, HID, b_lin_i, z_item, NI, DOUT);

    // ---- decode ----
    decode_kernel<<<(((NLBL + 1) / 2) * 64 + 255) / 256, 256, 0, stream>>>(
        edge_lbl, z_user, z_item, out, NLBL);
}

// Round 5
// 623.526 us; speedup vs baseline: 14.5421x; 1.0646x over previous
//
#include <hip/hip_runtime.h>

#define NU 50000
#define NI 50000
#define NE 800000
#define NLBL 200000
#define DIN 128
#define HID 256
#define DOUT 128

#define NSHARD 8
#define NODES_PER 6250   // 50000 / 8
#define FCHUNKS 64
#define FCHUNK_SZ 12500  // 800000 / 64

typedef unsigned short ushort_t;
typedef __attribute__((ext_vector_type(8))) short bf16x8;
typedef __attribute__((ext_vector_type(4))) float f32x4;

__device__ __forceinline__ float bf2f(unsigned int u_shifted) {
    union { unsigned int i; float f; } v;
    v.i = u_shifted;
    return v.f;
}
__device__ __forceinline__ float bf_lo(unsigned int u) { return bf2f(u << 16); }
__device__ __forceinline__ float bf_hi(unsigned int u) { return bf2f(u & 0xffff0000u); }
__device__ __forceinline__ ushort_t f2bf(float f) {
    union { float f; unsigned int i; } v;
    v.f = f;
    unsigned int r = (v.i + 0x7FFFu + ((v.i >> 16) & 1u)) >> 16;
    return (ushort_t)r;
}
__device__ __forceinline__ void load_lds16(const ushort_t* g, ushort_t* s) {
    __builtin_amdgcn_global_load_lds(
        (const __attribute__((address_space(1))) void*)g,
        (__attribute__((address_space(3))) void*)s, 16, 0, 0);
}

// ================= CSR build (XCD-sharded; blockIdx.x&7 ~ XCD round-robin) =================
// Sharding is a locality heuristic only: every (chunk, shard) pair is covered exactly
// once regardless of actual block->XCD mapping, so the result is always correct.
__global__ __launch_bounds__(256) void hist2(const int* __restrict__ dui,
                                             const int* __restrict__ diu,
                                             int* __restrict__ cnt_i, int* __restrict__ cnt_u) {
    const int* dst = blockIdx.y ? diu : dui;
    int* cnt = blockIdx.y ? cnt_u : cnt_i;
    const int sh = blockIdx.x & 7;
    const int chunk = blockIdx.x >> 3;
    const int lo = sh * NODES_PER, hi = lo + NODES_PER;
    const int end = (chunk + 1) * FCHUNK_SZ;
    for (int i = chunk * FCHUNK_SZ + threadIdx.x; i < end; i += 256) {
        int d = dst[i];
        if (d >= lo && d < hi) atomicAdd(&cnt[d], 1);
    }
}

__global__ __launch_bounds__(256) void fill2(const int* __restrict__ eui,
                                             const int* __restrict__ eiu,
                                             int* __restrict__ rp_i, int* __restrict__ rp_u,
                                             int* __restrict__ csr) {
    const int* src = blockIdx.y ? eiu : eui;
    const int* dst = src + NE;
    int* rp = blockIdx.y ? rp_u : rp_i;
    const int sh = blockIdx.x & 7;
    const int chunk = blockIdx.x >> 3;
    const int lo = sh * NODES_PER, hi = lo + NODES_PER;
    const int end = (chunk + 1) * FCHUNK_SZ;
    for (int i = chunk * FCHUNK_SZ + threadIdx.x; i < end; i += 256) {
        int d = dst[i];
        if (d >= lo && d < hi) {
            int p = atomicAdd(&rp[d], 1);
            csr[p] = src[i];
        }
    }
}

// ---- 3-phase exclusive scan over n ints ----
__global__ __launch_bounds__(256) void scan1(const int* __restrict__ d, int* __restrict__ part, int n) {
    __shared__ int wsum[4];
    int b = blockIdx.x, t = threadIdx.x;
    int i0 = b * 2048 + t * 8;
    int s = 0;
#pragma unroll
    for (int k = 0; k < 8; ++k) s += (i0 + k < n) ? d[i0 + k] : 0;
#pragma unroll
    for (int off = 32; off > 0; off >>= 1) s += __shfl_down(s, off, 64);
    if ((t & 63) == 0) wsum[t >> 6] = s;
    __syncthreads();
    if (t == 0) part[b] = wsum[0] + wsum[1] + wsum[2] + wsum[3];
}
__global__ __launch_bounds__(64) void scan2(int* __restrict__ part, int nb) {
    int lane = threadIdx.x;
    int v = (lane < nb) ? part[lane] : 0;
    int incl = v;
#pragma unroll
    for (int off = 1; off < 64; off <<= 1) {
        int t = __shfl_up(incl, off, 64);
        if (lane >= off) incl += t;
    }
    if (lane < nb) part[lane] = incl - v;
}
__global__ __launch_bounds__(256) void scan3(int* __restrict__ d, const int* __restrict__ part, int n) {
    __shared__ int wsum[4];
    int b = blockIdx.x, t = threadIdx.x;
    int lane = t & 63, wv = t >> 6;
    int i0 = b * 2048 + t * 8;
    int v[8];
    int tsum = 0;
#pragma unroll
    for (int k = 0; k < 8; ++k) {
        v[k] = (i0 + k < n) ? d[i0 + k] : 0;
        tsum += v[k];
    }
    int incl = tsum;
#pragma unroll
    for (int off = 1; off < 64; off <<= 1) {
        int tv = __shfl_up(incl, off, 64);
        if (lane >= off) incl += tv;
    }
    if (lane == 63) wsum[wv] = incl;
    __syncthreads();
    int woff = 0;
    for (int w = 0; w < wv; ++w) woff += wsum[w];
    int run = part[b] + woff + (incl - tsum);
#pragma unroll
    for (int k = 0; k < 8; ++k) {
        if (i0 + k < n) d[i0 + k] = run;
        run += v[k];
    }
}

// ================= conversions =================
__global__ void cvt2(const float* __restrict__ a, ushort_t* __restrict__ oa,
                     const float* __restrict__ b, ushort_t* __restrict__ ob, int n4) {
    const float4* in = (const float4*)(blockIdx.y ? b : a);
    uint2* outp = (uint2*)(blockIdx.y ? ob : oa);
    int i = blockIdx.x * blockDim.x + threadIdx.x;
    if (i < n4) {
        float4 v = in[i];
        uint2 o;
        o.x = (unsigned int)f2bf(v.x) | ((unsigned int)f2bf(v.y) << 16);
        o.y = (unsigned int)f2bf(v.z) | ((unsigned int)f2bf(v.w) << 16);
        outp[i] = o;
    }
}

struct TJob { const float* W; ushort_t* T; int K; int N; };
struct TJobs { TJob j[12]; };
__global__ void transpose_all(TJobs js) {
    TJob jb = js.j[blockIdx.y];
    int t = blockIdx.x * blockDim.x + threadIdx.x;
    if (t < jb.K * jb.N) {
        int k = t / jb.N, n = t - k * jb.N;
        jb.T[(size_t)n * jb.K + k] = f2bf(jb.W[t]);
    }
}

// ================= gather mean aggregation (bf16, fp32 accum), 2 jobs =================
// D==256: 2 waves per dst node (each handles 128 feats, 4B/lane); D==128: 1 wave.
// Unroll 8: 8 independent row-gathers in flight.
struct AggJob { const int* endptr; const int* csr; int s0_first; const ushort_t* x; ushort_t* out; int n; };
struct AggJobs2 { AggJob j[2]; };

template <int D>
__global__ __launch_bounds__(256) void agg2(AggJobs2 js) {
    AggJob jb = js.j[blockIdx.y];
    constexpr int SPLIT = (D == 256) ? 2 : 1;
    constexpr int RU = D / 2;  // row stride in uints
    int wg = (int)((blockIdx.x * 256u + threadIdx.x) >> 6);
    int lane = threadIdx.x & 63;
    int w = wg / SPLIT;
    int h = wg - w * SPLIT;
    if (w >= jb.n) return;
    int s0 = (w == 0) ? jb.s0_first : jb.endptr[w - 1];
    int s1 = jb.endptr[w];
    int cnt = s1 - s0;
    float sc = (cnt > 0) ? 1.0f / (float)cnt : 0.0f;
    const unsigned int* xp = (const unsigned int*)jb.x;
    const int col = h * 64 + lane;

    float a0 = 0.f, a1 = 0.f, b0 = 0.f, b1 = 0.f;
    float c0 = 0.f, c1 = 0.f, d0 = 0.f, d1 = 0.f;
    for (int chunk = 0; chunk < cnt; chunk += 64) {
        int m = cnt - chunk;
        if (m > 64) m = 64;
        int vidx = jb.csr[s0 + chunk + ((lane < m) ? lane : (m - 1))];
        int j = 0;
        for (; j + 7 < m; j += 8) {
            int i0 = __shfl(vidx, j, 64);
            int i1 = __shfl(vidx, j + 1, 64);
            int i2 = __shfl(vidx, j + 2, 64);
            int i3 = __shfl(vidx, j + 3, 64);
            int i4 = __shfl(vidx, j + 4, 64);
            int i5 = __shfl(vidx, j + 5, 64);
            int i6 = __shfl(vidx, j + 6, 64);
            int i7 = __shfl(vidx, j + 7, 64);
            unsigned int u0 = xp[(size_t)i0 * RU + col];
            unsigned int u1 = xp[(size_t)i1 * RU + col];
            unsigned int u2 = xp[(size_t)i2 * RU + col];
            unsigned int u3 = xp[(size_t)i3 * RU + col];
            unsigned int u4 = xp[(size_t)i4 * RU + col];
            unsigned int u5 = xp[(size_t)i5 * RU + col];
            unsigned int u6 = xp[(size_t)i6 * RU + col];
            unsigned int u7 = xp[(size_t)i7 * RU + col];
            a0 += bf_lo(u0) + bf_lo(u4); a1 += bf_hi(u0) + bf_hi(u4);
            b0 += bf_lo(u1) + bf_lo(u5); b1 += bf_hi(u1) + bf_hi(u5);
            c0 += bf_lo(u2) + bf_lo(u6); c1 += bf_hi(u2) + bf_hi(u6);
            d0 += bf_lo(u3) + bf_lo(u7); d1 += bf_hi(u3) + bf_hi(u7);
        }
        for (; j < m; ++j) {
            int i0 = __shfl(vidx, j, 64);
            unsigned int u0 = xp[(size_t)i0 * RU + col];
            a0 += bf_lo(u0); a1 += bf_hi(u0);
        }
    }
    float r0 = (a0 + b0 + c0 + d0) * sc;
    float r1 = (a1 + b1 + c1 + d1) * sc;
    unsigned int o = (unsigned int)f2bf(r0) | ((unsigned int)f2bf(r1) << 16);
    ((unsigned int*)jb.out)[(size_t)w * RU + col] = o;
}

// ================= MFMA GEMM: C = A1@W1 + A2@W2 + bias, 2 jobs via blockIdx.z =================
struct GemmJob {
    const ushort_t *A1, *W1T;
    int K1;
    const ushort_t *A2, *W2T;
    int K2;
    const float* bias;
    void* C;
};
struct GemmJobs2 { GemmJob j[2]; };

template <typename OutT>
__global__ __launch_bounds__(256) void gemm2(GemmJobs2 js, int M, int N) {
    GemmJob jb = js.j[blockIdx.z];
    __shared__ ushort_t sA[128 * 32];
    __shared__ ushort_t sB[128 * 32];
    const int tid = threadIdx.x;
    const int lane = tid & 63;
    const int wv = tid >> 6;
    const int wm = wv & 1, wn = wv >> 1;
    const int bm = blockIdx.y * 128, bn = blockIdx.x * 128;

    f32x4 acc[4][4] = {};

    const int srow = tid >> 2;
    const int scol = (tid & 3) * 8;

    for (int part = 0; part < 2; ++part) {
        const ushort_t* A = part ? jb.A2 : jb.A1;
        const ushort_t* WT = part ? jb.W2T : jb.W1T;
        const int K = part ? jb.K2 : jb.K1;
        int ar0 = bm + srow;       if (ar0 > M - 1) ar0 = M - 1;
        int ar1 = bm + 64 + srow;  if (ar1 > M - 1) ar1 = M - 1;
        const size_t aoff0 = (size_t)ar0 * K + scol;
        const size_t aoff1 = (size_t)ar1 * K + scol;
        const size_t boff0 = (size_t)(bn + srow) * K + scol;
        const size_t boff1 = (size_t)(bn + 64 + srow) * K + scol;
        for (int k0 = 0; k0 < K; k0 += 32) {
            __syncthreads();
            load_lds16(A + aoff0 + k0, sA + tid * 8);
            load_lds16(A + aoff1 + k0, sA + 2048 + tid * 8);
            load_lds16(WT + boff0 + k0, sB + tid * 8);
            load_lds16(WT + boff1 + k0, sB + 2048 + tid * 8);
            __syncthreads();
            const ushort_t* pA = sA + ((wm * 64 + (lane & 15)) * 32 + (lane >> 4) * 8);
            const ushort_t* pB = sB + ((wn * 64 + (lane & 15)) * 32 + (lane >> 4) * 8);
            bf16x8 af[4], bfr[4];
#pragma unroll
            for (int mt = 0; mt < 4; ++mt) af[mt] = *(const bf16x8*)(pA + mt * 512);
#pragma unroll
            for (int nt = 0; nt < 4; ++nt) bfr[nt] = *(const bf16x8*)(pB + nt * 512);
#pragma unroll
            for (int mt = 0; mt < 4; ++mt)
#pragma unroll
                for (int nt = 0; nt < 4; ++nt)
                    acc[mt][nt] = __builtin_amdgcn_mfma_f32_16x16x32_bf16(
                        af[mt], bfr[nt], acc[mt][nt], 0, 0, 0);
        }
    }

#pragma unroll
    for (int mt = 0; mt < 4; ++mt) {
#pragma unroll
        for (int r = 0; r < 4; ++r) {
            int row = bm + wm * 64 + mt * 16 + (lane >> 4) * 4 + r;
            if (row >= M) continue;
#pragma unroll
            for (int nt = 0; nt < 4; ++nt) {
                int col = bn + wn * 64 + nt * 16 + (lane & 15);
                float v = acc[mt][nt][r] + jb.bias[col];
                if constexpr (sizeof(OutT) == 2)
                    ((ushort_t*)jb.C)[(size_t)row * N + col] = f2bf(v);
                else
                    ((float*)jb.C)[(size_t)row * N + col] = v;
            }
        }
    }
}

// ================= decode: bf16 z, 2 edges per wave =================
__global__ void decode_kernel(const int* __restrict__ lbl, const ushort_t* __restrict__ zu,
                              const ushort_t* __restrict__ zi, float* __restrict__ out, int n) {
    int gid = blockIdx.x * blockDim.x + threadIdx.x;
    int wave = gid >> 6;
    int lane = threadIdx.x & 63;
    int half = lane >> 5;
    int l = lane & 31;
    int e = wave * 2 + half;
    if (e >= n) return;
    int u = lbl[e];
    int it = lbl[n + e];
    uint2 a = ((const uint2*)zu)[(size_t)u * 32 + l];
    uint2 b = ((const uint2*)zi)[(size_t)it * 32 + l];
    float s = bf_lo(a.x) * bf_lo(b.x) + bf_hi(a.x) * bf_hi(b.x) +
              bf_lo(a.y) * bf_lo(b.y) + bf_hi(a.y) * bf_hi(b.y);
#pragma unroll
    for (int off = 16; off > 0; off >>= 1) s += __shfl_down(s, off, 32);
    if (l == 0) out[e] = s;
}

extern "C" void kernel_launch(void* const* d_in, const int* in_sizes, int n_in,
                              void* d_out, int out_size, void* d_ws, size_t ws_size,
                              hipStream_t stream) {
    const float* x_user = (const float*)d_in[0];
    const float* x_item = (const float*)d_in[1];
    const int* edge_ui = (const int*)d_in[2];   // row0=src(user), row1=dst(item)
    const int* edge_iu = (const int*)d_in[3];   // row0=src(item), row1=dst(user)
    const int* edge_lbl = (const int*)d_in[4];
    const float* w_msg_ui0 = (const float*)d_in[5];
    const float* b_ui0 = (const float*)d_in[6];
    const float* w_root_ui0 = (const float*)d_in[7];
    const float* w_msg_iu0 = (const float*)d_in[8];
    const float* b_iu0 = (const float*)d_in[9];
    const float* w_root_iu0 = (const float*)d_in[10];
    const float* w_msg_ui1 = (const float*)d_in[11];
    const float* b_ui1 = (const float*)d_in[12];
    const float* w_root_ui1 = (const float*)d_in[13];
    const float* w_msg_iu1 = (const float*)d_in[14];
    const float* b_iu1 = (const float*)d_in[15];
    const float* w_root_iu1 = (const float*)d_in[16];
    const float* w_lin_u = (const float*)d_in[17];  // [512,128]
    const float* b_lin_u = (const float*)d_in[18];
    const float* w_lin_i = (const float*)d_in[19];
    const float* b_lin_i = (const float*)d_in[20];
    float* out = (float*)d_out;

    // ---- workspace layout ----
    char* p = (char*)d_ws;
    ushort_t* user0 = (ushort_t*)p;  p += (size_t)NU * HID * 2;
    ushort_t* item0 = (ushort_t*)p;  p += (size_t)NI * HID * 2;
    ushort_t* user1 = (ushort_t*)p;  p += (size_t)NU * HID * 2;
    ushort_t* item1 = (ushort_t*)p;  p += (size_t)NI * HID * 2;
    ushort_t* mean_a = (ushort_t*)p; p += (size_t)NI * HID * 2;  // item-side mean
    ushort_t* mean_b = (ushort_t*)p; p += (size_t)NU * HID * 2;  // user-side mean
    ushort_t* xb_u  = (ushort_t*)p;  p += (size_t)NU * DIN * 2;
    ushort_t* xb_i  = (ushort_t*)p;  p += (size_t)NI * DIN * 2;
    ushort_t* z_user = (ushort_t*)p; p += (size_t)NU * DOUT * 2;
    ushort_t* z_item = (ushort_t*)p; p += (size_t)NI * DOUT * 2;
    int* cnt_i      = (int*)p;       p += (size_t)NI * 4;
    int* cnt_u      = (int*)p;       p += (size_t)NU * 4;   // contiguous after cnt_i
    int* csr        = (int*)p;       p += (size_t)2 * NE * 4;  // [0,NE): ui; [NE,2NE): iu
    int* scan_part  = (int*)p;       p += 64 * 4;
    ushort_t* T_msg_ui0 = (ushort_t*)p; p += (size_t)DIN * HID * 2;
    ushort_t* T_root_ui0 = (ushort_t*)p; p += (size_t)DIN * HID * 2;
    ushort_t* T_msg_iu0 = (ushort_t*)p; p += (size_t)DIN * HID * 2;
    ushort_t* T_root_iu0 = (ushort_t*)p; p += (size_t)DIN * HID * 2;
    ushort_t* T_msg_ui1 = (ushort_t*)p; p += (size_t)HID * HID * 2;
    ushort_t* T_root_ui1 = (ushort_t*)p; p += (size_t)HID * HID * 2;
    ushort_t* T_msg_iu1 = (ushort_t*)p; p += (size_t)HID * HID * 2;
    ushort_t* T_root_iu1 = (ushort_t*)p; p += (size_t)HID * HID * 2;
    ushort_t* T_lin_u_a = (ushort_t*)p; p += (size_t)HID * DOUT * 2;
    ushort_t* T_lin_u_b = (ushort_t*)p; p += (size_t)HID * DOUT * 2;
    ushort_t* T_lin_i_a = (ushort_t*)p; p += (size_t)HID * DOUT * 2;
    ushort_t* T_lin_i_b = (ushort_t*)p; p += (size_t)HID * DOUT * 2;

    // ---- CSR build: sharded hist -> scan -> sharded fill ----
    const int NCNT = NI + NU;
    const int NB = (NCNT + 2047) / 2048;  // 49
    hipMemsetAsync(cnt_i, 0, (size_t)NCNT * sizeof(int), stream);
    hist2<<<dim3(NSHARD * FCHUNKS, 2), 256, 0, stream>>>(edge_ui + NE, edge_iu + NE, cnt_i, cnt_u);
    scan1<<<NB, 256, 0, stream>>>(cnt_i, scan_part, NCNT);
    scan2<<<1, 64, 0, stream>>>(scan_part, NB);
    scan3<<<NB, 256, 0, stream>>>(cnt_i, scan_part, NCNT);
    fill2<<<dim3(NSHARD * FCHUNKS, 2), 256, 0, stream>>>(edge_ui, edge_iu, cnt_i, cnt_u, csr);
    // cnt_i/cnt_u now hold absolute row END offsets into csr.

    // ---- convert inputs & weights to bf16 ----
    cvt2<<<dim3((NU * DIN / 4 + 255) / 256, 2), 256, 0, stream>>>(
        x_user, xb_u, x_item, xb_i, NU * DIN / 4);
    TJobs jobs = {{
        {w_msg_ui0, T_msg_ui0, DIN, HID}, {w_root_ui0, T_root_ui0, DIN, HID},
        {w_msg_iu0, T_msg_iu0, DIN, HID}, {w_root_iu0, T_root_iu0, DIN, HID},
        {w_msg_ui1, T_msg_ui1, HID, HID}, {w_root_ui1, T_root_ui1, HID, HID},
        {w_msg_iu1, T_msg_iu1, HID, HID}, {w_root_iu1, T_root_iu1, HID, HID},
        {w_lin_u, T_lin_u_a, HID, DOUT}, {w_lin_u + (size_t)HID * DOUT, T_lin_u_b, HID, DOUT},
        {w_lin_i, T_lin_i_a, HID, DOUT}, {w_lin_i + (size_t)HID * DOUT, T_lin_i_b, HID, DOUT},
    }};
    transpose_all<<<dim3((HID * HID + 255) / 256, 12), 256, 0, stream>>>(jobs);

    // ---- layer 0: both aggs in one launch, both GEMMs in one launch ----
    {
        AggJobs2 aj = {{{cnt_i, csr, 0, xb_u, mean_a, NI},
                        {cnt_u, csr, NE, xb_i, mean_b, NU}}};
        agg2<DIN><<<dim3((NI + 3) / 4, 2), 256, 0, stream>>>(aj);
        GemmJobs2 gj = {{{mean_a, T_msg_ui0, DIN, xb_i, T_root_ui0, DIN, b_ui0, item0},
                         {mean_b, T_msg_iu0, DIN, xb_u, T_root_iu0, DIN, b_iu0, user0}}};
        gemm2<ushort_t><<<dim3(HID / 128, (NI + 127) / 128, 2), 256, 0, stream>>>(gj, NI, HID);
    }

    // ---- layer 1 ----
    {
        AggJobs2 aj = {{{cnt_i, csr, 0, user0, mean_a, NI},
                        {cnt_u, csr, NE, item0, mean_b, NU}}};
        agg2<HID><<<dim3((NI * 2 + 3) / 4, 2), 256, 0, stream>>>(aj);
        GemmJobs2 gj = {{{mean_a, T_msg_ui1, HID, item0, T_root_ui1, HID, b_ui1, item1},
                         {mean_b, T_msg_iu1, HID, user0, T_root_iu1, HID, b_iu1, user1}}};
        gemm2<ushort_t><<<dim3(HID / 128, (NI + 127) / 128, 2), 256, 0, stream>>>(gj, NI, HID);
    }

    // ---- JK concat + per-type linear ----
    {
        GemmJobs2 gj = {{{user0, T_lin_u_a, HID, user1, T_lin_u_b, HID, b_lin_u, z_user},
                         {item0, T_lin_i_a, HID, item1, T_lin_i_b, HID, b_lin_i, z_item}}};
        gemm2<ushort_t><<<dim3(DOUT / 128, (NU + 127) / 128, 2), 256, 0, stream>>>(gj, NU, DOUT);
    }

    // ---- decode ----
    decode_kernel<<<(((NLBL + 1) / 2) * 64 + 255) / 256, 256, 0, stream>>>(
        edge_lbl, z_user, z_item, out, NLBL);
}

// Round 6
// 588.206 us; speedup vs baseline: 15.4153x; 1.0600x over previous
//
#include <hip/hip_runtime.h>

#define NU 50000
#define NI 50000
#define NE 800000
#define NLBL 200000
#define DIN 128
#define HID 256
#define DOUT 128

#define NSHARD 8
#define NODES_PER 6250   // 50000 / 8
#define FCHUNKS 64
#define FCHUNK_SZ 12500  // 800000 / 64

typedef unsigned short ushort_t;
typedef __attribute__((ext_vector_type(8))) short bf16x8;
typedef __attribute__((ext_vector_type(4))) float f32x4;

__device__ __forceinline__ float bf2f(unsigned int u_shifted) {
    union { unsigned int i; float f; } v;
    v.i = u_shifted;
    return v.f;
}
__device__ __forceinline__ float bf_lo(unsigned int u) { return bf2f(u << 16); }
__device__ __forceinline__ float bf_hi(unsigned int u) { return bf2f(u & 0xffff0000u); }
__device__ __forceinline__ ushort_t f2bf(float f) {
    union { float f; unsigned int i; } v;
    v.f = f;
    unsigned int r = (v.i + 0x7FFFu + ((v.i >> 16) & 1u)) >> 16;
    return (ushort_t)r;
}
__device__ __forceinline__ void load_lds16(const ushort_t* g, ushort_t* s) {
    __builtin_amdgcn_global_load_lds(
        (const __attribute__((address_space(1))) void*)g,
        (__attribute__((address_space(3))) void*)s, 16, 0, 0);
}

// ================= fused prep: sharded hist + input cvt + weight transpose =================
// Independent jobs packed into one launch by blockIdx.x range.
// [0,1024): hist (XCD-sharded) | [1024,1024+1564): cvt | rest: transpose (12 jobs)
#define HIST_B 1024
#define CVT_PER 782          // ceil(1.6e6 float4 / 2048)
#define CVT_B (2 * CVT_PER)
#define TR_B 2048            // 4*128 + 4*256 + 4*128 blocks, 256 elems each

struct TJob { const float* W; ushort_t* T; int K; int N; };
struct PrepArgs {
    const int* dui; const int* diu; int* cnt_i; int* cnt_u;
    const float* xu; ushort_t* xbu; const float* xi; ushort_t* xbi;
    TJob tj[12];
};

__global__ __launch_bounds__(256) void prep_kernel(PrepArgs a) {
    int b = blockIdx.x;
    int t = threadIdx.x;
    if (b < HIST_B) {
        // ---- sharded histogram (locality heuristic: blockIdx&7 ~ XCD round-robin;
        // correct regardless of actual block->XCD mapping) ----
        int which = b >> 9;          // 0: ui->item counts, 1: iu->user counts
        int xb = b & 511;
        const int* dst = which ? a.diu : a.dui;
        int* cnt = which ? a.cnt_u : a.cnt_i;
        int sh = xb & 7, chunk = xb >> 3;
        int lo = sh * NODES_PER, hi = lo + NODES_PER;
        int end = (chunk + 1) * FCHUNK_SZ;
        for (int i = chunk * FCHUNK_SZ + t; i < end; i += 256) {
            int d = dst[i];
            if (d >= lo && d < hi) atomicAdd(&cnt[d], 1);
        }
    } else if (b < HIST_B + CVT_B) {
        // ---- fp32 -> bf16 input conversion ----
        int cb = b - HIST_B;
        int which = (cb >= CVT_PER);
        if (which) cb -= CVT_PER;
        const float4* in = (const float4*)(which ? a.xi : a.xu);
        uint2* outp = (uint2*)(which ? a.xbi : a.xbu);
        const int n4 = NU * DIN / 4;
#pragma unroll
        for (int k = 0; k < 8; ++k) {
            int i = cb * 2048 + k * 256 + t;
            if (i < n4) {
                float4 v = in[i];
                uint2 o;
                o.x = (unsigned int)f2bf(v.x) | ((unsigned int)f2bf(v.y) << 16);
                o.y = (unsigned int)f2bf(v.z) | ((unsigned int)f2bf(v.w) << 16);
                outp[i] = o;
            }
        }
    } else {
        // ---- weight transpose+convert: W [K][N] f32 -> T [N][K] bf16 ----
        int r = b - HIST_B - CVT_B;
        int j = 0, acc = 0;
        for (; j < 12; ++j) {
            int nb = (a.tj[j].K * a.tj[j].N) >> 8;
            if (r < acc + nb) break;
            acc += nb;
        }
        TJob jb = a.tj[j];
        int e = (r - acc) * 256 + t;
        int k = e / jb.N, n = e - k * jb.N;
        jb.T[(size_t)n * jb.K + k] = f2bf(jb.W[e]);
    }
}

// ---- scan phase 1: per-block sums ----
__global__ __launch_bounds__(256) void scan1(const int* __restrict__ d, int* __restrict__ part, int n) {
    __shared__ int wsum[4];
    int b = blockIdx.x, t = threadIdx.x;
    int i0 = b * 2048 + t * 8;
    int s = 0;
#pragma unroll
    for (int k = 0; k < 8; ++k) s += (i0 + k < n) ? d[i0 + k] : 0;
#pragma unroll
    for (int off = 32; off > 0; off >>= 1) s += __shfl_down(s, off, 64);
    if ((t & 63) == 0) wsum[t >> 6] = s;
    __syncthreads();
    if (t == 0) part[b] = wsum[0] + wsum[1] + wsum[2] + wsum[3];
}

// ---- scan phase 2: block-local exclusive scan; each block redundantly scans partials ----
__global__ __launch_bounds__(256) void scan3(int* __restrict__ d, const int* __restrict__ part,
                                             int n, int nb) {
    __shared__ int wsum[4];
    __shared__ int blockoff_sh;
    int b = blockIdx.x, t = threadIdx.x;
    int lane = t & 63, wv = t >> 6;
    if (t < 64) {
        int v = (t < nb) ? part[t] : 0;
        int incl = v;
#pragma unroll
        for (int off = 1; off < 64; off <<= 1) {
            int tv = __shfl_up(incl, off, 64);
            if (t >= off) incl += tv;
        }
        if (t == b) blockoff_sh = incl - v;  // exclusive prefix of part[b]
    }
    int i0 = b * 2048 + t * 8;
    int v[8];
    int tsum = 0;
#pragma unroll
    for (int k = 0; k < 8; ++k) {
        v[k] = (i0 + k < n) ? d[i0 + k] : 0;
        tsum += v[k];
    }
    int incl = tsum;
#pragma unroll
    for (int off = 1; off < 64; off <<= 1) {
        int tv = __shfl_up(incl, off, 64);
        if (lane >= off) incl += tv;
    }
    if (lane == 63) wsum[wv] = incl;
    __syncthreads();
    int woff = 0;
    for (int w = 0; w < wv; ++w) woff += wsum[w];
    int run = blockoff_sh + woff + (incl - tsum);
#pragma unroll
    for (int k = 0; k < 8; ++k) {
        if (i0 + k < n) d[i0 + k] = run;
        run += v[k];
    }
}

// ---- sharded CSR fill ----
__global__ __launch_bounds__(256) void fill2(const int* __restrict__ eui,
                                             const int* __restrict__ eiu,
                                             int* __restrict__ rp_i, int* __restrict__ rp_u,
                                             int* __restrict__ csr) {
    const int* src = blockIdx.y ? eiu : eui;
    const int* dst = src + NE;
    int* rp = blockIdx.y ? rp_u : rp_i;
    const int sh = blockIdx.x & 7;
    const int chunk = blockIdx.x >> 3;
    const int lo = sh * NODES_PER, hi = lo + NODES_PER;
    const int end = (chunk + 1) * FCHUNK_SZ;
    for (int i = chunk * FCHUNK_SZ + threadIdx.x; i < end; i += 256) {
        int d = dst[i];
        if (d >= lo && d < hi) {
            int p = atomicAdd(&rp[d], 1);
            csr[p] = src[i];
        }
    }
}

// ================= gather mean aggregation (bf16, fp32 accum), 2 jobs =================
// One wave per dst row. D==256: uint2/lane (512B row); D==128: uint/lane (256B row).
struct AggJob { const int* endptr; const int* csr; int s0_first; const ushort_t* x; ushort_t* out; int n; };
struct AggJobs2 { AggJob j[2]; };

template <int D>
__global__ __launch_bounds__(256) void agg2(AggJobs2 js) {
    AggJob jb = js.j[blockIdx.y];
    int w = (int)((blockIdx.x * 256u + threadIdx.x) >> 6);
    int lane = threadIdx.x & 63;
    if (w >= jb.n) return;
    int s0 = (w == 0) ? jb.s0_first : jb.endptr[w - 1];
    int s1 = jb.endptr[w];
    int cnt = s1 - s0;
    float sc = (cnt > 0) ? 1.0f / (float)cnt : 0.0f;

    if constexpr (D == 256) {
        const uint2* xp = (const uint2*)jb.x;  // row = 64 uint2
        float f0 = 0.f, f1 = 0.f, f2 = 0.f, f3 = 0.f;
        float g0 = 0.f, g1 = 0.f, g2 = 0.f, g3 = 0.f;
        for (int chunk = 0; chunk < cnt; chunk += 64) {
            int m = cnt - chunk;
            if (m > 64) m = 64;
            int vidx = jb.csr[s0 + chunk + ((lane < m) ? lane : (m - 1))];
            int j = 0;
            for (; j + 3 < m; j += 4) {
                int i0 = __shfl(vidx, j, 64);
                int i1 = __shfl(vidx, j + 1, 64);
                int i2 = __shfl(vidx, j + 2, 64);
                int i3 = __shfl(vidx, j + 3, 64);
                uint2 v0 = xp[(size_t)i0 * 64 + lane];
                uint2 v1 = xp[(size_t)i1 * 64 + lane];
                uint2 v2 = xp[(size_t)i2 * 64 + lane];
                uint2 v3 = xp[(size_t)i3 * 64 + lane];
                f0 += bf_lo(v0.x) + bf_lo(v2.x); f1 += bf_hi(v0.x) + bf_hi(v2.x);
                f2 += bf_lo(v0.y) + bf_lo(v2.y); f3 += bf_hi(v0.y) + bf_hi(v2.y);
                g0 += bf_lo(v1.x) + bf_lo(v3.x); g1 += bf_hi(v1.x) + bf_hi(v3.x);
                g2 += bf_lo(v1.y) + bf_lo(v3.y); g3 += bf_hi(v1.y) + bf_hi(v3.y);
            }
            for (; j < m; ++j) {
                int i0 = __shfl(vidx, j, 64);
                uint2 v0 = xp[(size_t)i0 * 64 + lane];
                f0 += bf_lo(v0.x); f1 += bf_hi(v0.x);
                f2 += bf_lo(v0.y); f3 += bf_hi(v0.y);
            }
        }
        uint2 o;
        o.x = (unsigned int)f2bf((f0 + g0) * sc) | ((unsigned int)f2bf((f1 + g1) * sc) << 16);
        o.y = (unsigned int)f2bf((f2 + g2) * sc) | ((unsigned int)f2bf((f3 + g3) * sc) << 16);
        ((uint2*)jb.out)[(size_t)w * 64 + lane] = o;
    } else {
        const unsigned int* xp = (const unsigned int*)jb.x;  // row = 64 uints
        float a0 = 0.f, a1 = 0.f, b0 = 0.f, b1 = 0.f;
        float c0 = 0.f, c1 = 0.f, d0 = 0.f, d1 = 0.f;
        for (int chunk = 0; chunk < cnt; chunk += 64) {
            int m = cnt - chunk;
            if (m > 64) m = 64;
            int vidx = jb.csr[s0 + chunk + ((lane < m) ? lane : (m - 1))];
            int j = 0;
            for (; j + 7 < m; j += 8) {
                int i0 = __shfl(vidx, j, 64);
                int i1 = __shfl(vidx, j + 1, 64);
                int i2 = __shfl(vidx, j + 2, 64);
                int i3 = __shfl(vidx, j + 3, 64);
                int i4 = __shfl(vidx, j + 4, 64);
                int i5 = __shfl(vidx, j + 5, 64);
                int i6 = __shfl(vidx, j + 6, 64);
                int i7 = __shfl(vidx, j + 7, 64);
                unsigned int u0 = xp[(size_t)i0 * 64 + lane];
                unsigned int u1 = xp[(size_t)i1 * 64 + lane];
                unsigned int u2 = xp[(size_t)i2 * 64 + lane];
                unsigned int u3 = xp[(size_t)i3 * 64 + lane];
                unsigned int u4 = xp[(size_t)i4 * 64 + lane];
                unsigned int u5 = xp[(size_t)i5 * 64 + lane];
                unsigned int u6 = xp[(size_t)i6 * 64 + lane];
                unsigned int u7 = xp[(size_t)i7 * 64 + lane];
                a0 += bf_lo(u0) + bf_lo(u4); a1 += bf_hi(u0) + bf_hi(u4);
                b0 += bf_lo(u1) + bf_lo(u5); b1 += bf_hi(u1) + bf_hi(u5);
                c0 += bf_lo(u2) + bf_lo(u6); c1 += bf_hi(u2) + bf_hi(u6);
                d0 += bf_lo(u3) + bf_lo(u7); d1 += bf_hi(u3) + bf_hi(u7);
            }
            for (; j < m; ++j) {
                int i0 = __shfl(vidx, j, 64);
                unsigned int u0 = xp[(size_t)i0 * 64 + lane];
                a0 += bf_lo(u0); a1 += bf_hi(u0);
            }
        }
        float r0 = (a0 + b0 + c0 + d0) * sc;
        float r1 = (a1 + b1 + c1 + d1) * sc;
        unsigned int o = (unsigned int)f2bf(r0) | ((unsigned int)f2bf(r1) << 16);
        ((unsigned int*)jb.out)[(size_t)w * 64 + lane] = o;
    }
}

// ================= MFMA GEMM: C = A1@W1 + A2@W2 + bias, 2 jobs via blockIdx.z =================
struct GemmJob {
    const ushort_t *A1, *W1T;
    int K1;
    const ushort_t *A2, *W2T;
    int K2;
    const float* bias;
    void* C;
};
struct GemmJobs2 { GemmJob j[2]; };

template <typename OutT>
__global__ __launch_bounds__(256) void gemm2(GemmJobs2 js, int M, int N) {
    GemmJob jb = js.j[blockIdx.z];
    __shared__ ushort_t sA[128 * 32];
    __shared__ ushort_t sB[128 * 32];
    const int tid = threadIdx.x;
    const int lane = tid & 63;
    const int wv = tid >> 6;
    const int wm = wv & 1, wn = wv >> 1;
    const int bm = blockIdx.y * 128, bn = blockIdx.x * 128;

    f32x4 acc[4][4] = {};

    const int srow = tid >> 2;
    const int scol = (tid & 3) * 8;

    for (int part = 0; part < 2; ++part) {
        const ushort_t* A = part ? jb.A2 : jb.A1;
        const ushort_t* WT = part ? jb.W2T : jb.W1T;
        const int K = part ? jb.K2 : jb.K1;
        int ar0 = bm + srow;       if (ar0 > M - 1) ar0 = M - 1;
        int ar1 = bm + 64 + srow;  if (ar1 > M - 1) ar1 = M - 1;
        const size_t aoff0 = (size_t)ar0 * K + scol;
        const size_t aoff1 = (size_t)ar1 * K + scol;
        const size_t boff0 = (size_t)(bn + srow) * K + scol;
        const size_t boff1 = (size_t)(bn + 64 + srow) * K + scol;
        for (int k0 = 0; k0 < K; k0 += 32) {
            __syncthreads();
            load_lds16(A + aoff0 + k0, sA + tid * 8);
            load_lds16(A + aoff1 + k0, sA + 2048 + tid * 8);
            load_lds16(WT + boff0 + k0, sB + tid * 8);
            load_lds16(WT + boff1 + k0, sB + 2048 + tid * 8);
            __syncthreads();
            const ushort_t* pA = sA + ((wm * 64 + (lane & 15)) * 32 + (lane >> 4) * 8);
            const ushort_t* pB = sB + ((wn * 64 + (lane & 15)) * 32 + (lane >> 4) * 8);
            bf16x8 af[4], bfr[4];
#pragma unroll
            for (int mt = 0; mt < 4; ++mt) af[mt] = *(const bf16x8*)(pA + mt * 512);
#pragma unroll
            for (int nt = 0; nt < 4; ++nt) bfr[nt] = *(const bf16x8*)(pB + nt * 512);
#pragma unroll
            for (int mt = 0; mt < 4; ++mt)
#pragma unroll
                for (int nt = 0; nt < 4; ++nt)
                    acc[mt][nt] = __builtin_amdgcn_mfma_f32_16x16x32_bf16(
                        af[mt], bfr[nt], acc[mt][nt], 0, 0, 0);
        }
    }

#pragma unroll
    for (int mt = 0; mt < 4; ++mt) {
#pragma unroll
        for (int r = 0; r < 4; ++r) {
            int row = bm + wm * 64 + mt * 16 + (lane >> 4) * 4 + r;
            if (row >= M) continue;
#pragma unroll
            for (int nt = 0; nt < 4; ++nt) {
                int col = bn + wn * 64 + nt * 16 + (lane & 15);
                float v = acc[mt][nt][r] + jb.bias[col];
                if constexpr (sizeof(OutT) == 2)
                    ((ushort_t*)jb.C)[(size_t)row * N + col] = f2bf(v);
                else
                    ((float*)jb.C)[(size_t)row * N + col] = v;
            }
        }
    }
}

// ================= decode: bf16 z, 2 edges per wave =================
__global__ void decode_kernel(const int* __restrict__ lbl, const ushort_t* __restrict__ zu,
                              const ushort_t* __restrict__ zi, float* __restrict__ out, int n) {
    int gid = blockIdx.x * blockDim.x + threadIdx.x;
    int wave = gid >> 6;
    int lane = threadIdx.x & 63;
    int half = lane >> 5;
    int l = lane & 31;
    int e = wave * 2 + half;
    if (e >= n) return;
    int u = lbl[e];
    int it = lbl[n + e];
    uint2 a = ((const uint2*)zu)[(size_t)u * 32 + l];
    uint2 b = ((const uint2*)zi)[(size_t)it * 32 + l];
    float s = bf_lo(a.x) * bf_lo(b.x) + bf_hi(a.x) * bf_hi(b.x) +
              bf_lo(a.y) * bf_lo(b.y) + bf_hi(a.y) * bf_hi(b.y);
#pragma unroll
    for (int off = 16; off > 0; off >>= 1) s += __shfl_down(s, off, 32);
    if (l == 0) out[e] = s;
}

extern "C" void kernel_launch(void* const* d_in, const int* in_sizes, int n_in,
                              void* d_out, int out_size, void* d_ws, size_t ws_size,
                              hipStream_t stream) {
    const float* x_user = (const float*)d_in[0];
    const float* x_item = (const float*)d_in[1];
    const int* edge_ui = (const int*)d_in[2];   // row0=src(user), row1=dst(item)
    const int* edge_iu = (const int*)d_in[3];   // row0=src(item), row1=dst(user)
    const int* edge_lbl = (const int*)d_in[4];
    const float* w_msg_ui0 = (const float*)d_in[5];
    const float* b_ui0 = (const float*)d_in[6];
    const float* w_root_ui0 = (const float*)d_in[7];
    const float* w_msg_iu0 = (const float*)d_in[8];
    const float* b_iu0 = (const float*)d_in[9];
    const float* w_root_iu0 = (const float*)d_in[10];
    const float* w_msg_ui1 = (const float*)d_in[11];
    const float* b_ui1 = (const float*)d_in[12];
    const float* w_root_ui1 = (const float*)d_in[13];
    const float* w_msg_iu1 = (const float*)d_in[14];
    const float* b_iu1 = (const float*)d_in[15];
    const float* w_root_iu1 = (const float*)d_in[16];
    const float* w_lin_u = (const float*)d_in[17];  // [512,128]
    const float* b_lin_u = (const float*)d_in[18];
    const float* w_lin_i = (const float*)d_in[19];
    const float* b_lin_i = (const float*)d_in[20];
    float* out = (float*)d_out;

    // ---- workspace layout ----
    char* p = (char*)d_ws;
    ushort_t* user0 = (ushort_t*)p;  p += (size_t)NU * HID * 2;
    ushort_t* item0 = (ushort_t*)p;  p += (size_t)NI * HID * 2;
    ushort_t* user1 = (ushort_t*)p;  p += (size_t)NU * HID * 2;
    ushort_t* item1 = (ushort_t*)p;  p += (size_t)NI * HID * 2;
    ushort_t* mean_a = (ushort_t*)p; p += (size_t)NI * HID * 2;
    ushort_t* mean_b = (ushort_t*)p; p += (size_t)NU * HID * 2;
    ushort_t* xb_u  = (ushort_t*)p;  p += (size_t)NU * DIN * 2;
    ushort_t* xb_i  = (ushort_t*)p;  p += (size_t)NI * DIN * 2;
    ushort_t* z_user = (ushort_t*)p; p += (size_t)NU * DOUT * 2;
    ushort_t* z_item = (ushort_t*)p; p += (size_t)NI * DOUT * 2;
    int* cnt_i      = (int*)p;       p += (size_t)NI * 4;
    int* cnt_u      = (int*)p;       p += (size_t)NU * 4;   // contiguous after cnt_i
    int* csr        = (int*)p;       p += (size_t)2 * NE * 4;  // [0,NE): ui; [NE,2NE): iu
    int* scan_part  = (int*)p;       p += 64 * 4;
    ushort_t* T_msg_ui0 = (ushort_t*)p; p += (size_t)DIN * HID * 2;
    ushort_t* T_root_ui0 = (ushort_t*)p; p += (size_t)DIN * HID * 2;
    ushort_t* T_msg_iu0 = (ushort_t*)p; p += (size_t)DIN * HID * 2;
    ushort_t* T_root_iu0 = (ushort_t*)p; p += (size_t)DIN * HID * 2;
    ushort_t* T_msg_ui1 = (ushort_t*)p; p += (size_t)HID * HID * 2;
    ushort_t* T_root_ui1 = (ushort_t*)p; p += (size_t)HID * HID * 2;
    ushort_t* T_msg_iu1 = (ushort_t*)p; p += (size_t)HID * HID * 2;
    ushort_t* T_root_iu1 = (ushort_t*)p; p += (size_t)HID * HID * 2;
    ushort_t* T_lin_u_a = (ushort_t*)p; p += (size_t)HID * DOUT * 2;
    ushort_t* T_lin_u_b = (ushort_t*)p; p += (size_t)HID * DOUT * 2;
    ushort_t* T_lin_i_a = (ushort_t*)p; p += (size_t)HID * DOUT * 2;
    ushort_t* T_lin_i_b = (ushort_t*)p; p += (size_t)HID * DOUT * 2;

    const int NCNT = NI + NU;
    const int NB = (NCNT + 2047) / 2048;  // 49

    // ---- fused prep (hist + cvt + transpose) ----
    hipMemsetAsync(cnt_i, 0, (size_t)NCNT * sizeof(int), stream);
    PrepArgs pa;
    pa.dui = edge_ui + NE; pa.diu = edge_iu + NE; pa.cnt_i = cnt_i; pa.cnt_u = cnt_u;
    pa.xu = x_user; pa.xbu = xb_u; pa.xi = x_item; pa.xbi = xb_i;
    TJob tj[12] = {
        {w_msg_ui0, T_msg_ui0, DIN, HID}, {w_root_ui0, T_root_ui0, DIN, HID},
        {w_msg_iu0, T_msg_iu0, DIN, HID}, {w_root_iu0, T_root_iu0, DIN, HID},
        {w_msg_ui1, T_msg_ui1, HID, HID}, {w_root_ui1, T_root_ui1, HID, HID},
        {w_msg_iu1, T_msg_iu1, HID, HID}, {w_root_iu1, T_root_iu1, HID, HID},
        {w_lin_u, T_lin_u_a, HID, DOUT}, {w_lin_u + (size_t)HID * DOUT, T_lin_u_b, HID, DOUT},
        {w_lin_i, T_lin_i_a, HID, DOUT}, {w_lin_i + (size_t)HID * DOUT, T_lin_i_b, HID, DOUT},
    };
    for (int j = 0; j < 12; ++j) pa.tj[j] = tj[j];
    prep_kernel<<<HIST_B + CVT_B + TR_B, 256, 0, stream>>>(pa);

    // ---- scan + fill ----
    scan1<<<NB, 256, 0, stream>>>(cnt_i, scan_part, NCNT);
    scan3<<<NB, 256, 0, stream>>>(cnt_i, scan_part, NCNT, NB);
    fill2<<<dim3(NSHARD * FCHUNKS, 2), 256, 0, stream>>>(edge_ui, edge_iu, cnt_i, cnt_u, csr);
    // cnt_i/cnt_u now hold absolute row END offsets into csr.

    // ---- layer 0 ----
    {
        AggJobs2 aj = {{{cnt_i, csr, 0, xb_u, mean_a, NI},
                        {cnt_u, csr, NE, xb_i, mean_b, NU}}};
        agg2<DIN><<<dim3((NI + 3) / 4, 2), 256, 0, stream>>>(aj);
        GemmJobs2 gj = {{{mean_a, T_msg_ui0, DIN, xb_i, T_root_ui0, DIN, b_ui0, item0},
                         {mean_b, T_msg_iu0, DIN, xb_u, T_root_iu0, DIN, b_iu0, user0}}};
        gemm2<ushort_t><<<dim3(HID / 128, (NI + 127) / 128, 2), 256, 0, stream>>>(gj, NI, HID);
    }

    // ---- layer 1 ----
    {
        AggJobs2 aj = {{{cnt_i, csr, 0, user0, mean_a, NI},
                        {cnt_u, csr, NE, item0, mean_b, NU}}};
        agg2<HID><<<dim3((NI + 3) / 4, 2), 256, 0, stream>>>(aj);
        GemmJobs2 gj = {{{mean_a, T_msg_ui1, HID, item0, T_root_ui1, HID, b_ui1, item1},
                         {mean_b, T_msg_iu1, HID, user0, T_root_iu1, HID, b_iu1, user1}}};
        gemm2<ushort_t><<<dim3(HID / 128, (NI + 127) / 128, 2), 256, 0, stream>>>(gj, NI, HID);
    }

    // ---- JK concat + per-type linear ----
    {
        GemmJobs2 gj = {{{user0, T_lin_u_a, HID, user1, T_lin_u_b, HID, b_lin_u, z_user},
                         {item0, T_lin_i_a, HID, item1, T_lin_i_b, HID, b_lin_i, z_item}}};
        gemm2<ushort_t><<<dim3(DOUT / 128, (NU + 127) / 128, 2), 256, 0, stream>>>(gj, NU, DOUT);
    }

    // ---- decode ----
    decode_kernel<<<(((NLBL + 1) / 2) * 64 + 255) / 256, 256, 0, stream>>>(
        edge_lbl, z_user, z_item, out, NLBL);
}

// Round 7
// 573.910 us; speedup vs baseline: 15.7993x; 1.0249x over previous
//
#include <hip/hip_runtime.h>

#define NU 50000
#define NI 50000
#define NE 800000
#define NLBL 200000
#define DIN 128
#define HID 256
#define DOUT 128

#define NSHARD 8
#define NODES_PER 6250   // 50000 / 8
#define FCHUNKS 64
#define FCHUNK_SZ 12500  // 800000 / 64

typedef unsigned short ushort_t;
typedef __attribute__((ext_vector_type(8))) short bf16x8;
typedef __attribute__((ext_vector_type(4))) float f32x4;

__device__ __forceinline__ float bf2f(unsigned int u_shifted) {
    union { unsigned int i; float f; } v;
    v.i = u_shifted;
    return v.f;
}
__device__ __forceinline__ float bf_lo(unsigned int u) { return bf2f(u << 16); }
__device__ __forceinline__ float bf_hi(unsigned int u) { return bf2f(u & 0xffff0000u); }
__device__ __forceinline__ ushort_t f2bf(float f) {
    union { float f; unsigned int i; } v;
    v.f = f;
    unsigned int r = (v.i + 0x7FFFu + ((v.i >> 16) & 1u)) >> 16;
    return (ushort_t)r;
}
__device__ __forceinline__ void load_lds16(const ushort_t* g, ushort_t* s) {
    __builtin_amdgcn_global_load_lds(
        (const __attribute__((address_space(1))) void*)g,
        (__attribute__((address_space(3))) void*)s, 16, 0, 0);
}

// ================= fused prep: sharded hist + input cvt + weight transpose =================
#define HIST_B 1024
#define CVT_PER 782
#define CVT_B (2 * CVT_PER)
#define TR_B 2048

struct TJob { const float* W; ushort_t* T; int K; int N; };
struct PrepArgs {
    const int* dui; const int* diu; int* cnt_i; int* cnt_u;
    const float* xu; ushort_t* xbu; const float* xi; ushort_t* xbi;
    TJob tj[12];
};

__global__ __launch_bounds__(256) void prep_kernel(PrepArgs a) {
    int b = blockIdx.x;
    int t = threadIdx.x;
    if (b < HIST_B) {
        // sharded histogram (blockIdx&7 ~ XCD round-robin; correctness independent of mapping)
        int which = b >> 9;
        int xb = b & 511;
        const int* dst = which ? a.diu : a.dui;
        int* cnt = which ? a.cnt_u : a.cnt_i;
        int sh = xb & 7, chunk = xb >> 3;
        int lo = sh * NODES_PER, hi = lo + NODES_PER;
        int end = (chunk + 1) * FCHUNK_SZ;
        for (int i = chunk * FCHUNK_SZ + t; i < end; i += 256) {
            int d = dst[i];
            if (d >= lo && d < hi) atomicAdd(&cnt[d], 1);
        }
    } else if (b < HIST_B + CVT_B) {
        int cb = b - HIST_B;
        int which = (cb >= CVT_PER);
        if (which) cb -= CVT_PER;
        const float4* in = (const float4*)(which ? a.xi : a.xu);
        uint2* outp = (uint2*)(which ? a.xbi : a.xbu);
        const int n4 = NU * DIN / 4;
#pragma unroll
        for (int k = 0; k < 8; ++k) {
            int i = cb * 2048 + k * 256 + t;
            if (i < n4) {
                float4 v = in[i];
                uint2 o;
                o.x = (unsigned int)f2bf(v.x) | ((unsigned int)f2bf(v.y) << 16);
                o.y = (unsigned int)f2bf(v.z) | ((unsigned int)f2bf(v.w) << 16);
                outp[i] = o;
            }
        }
    } else {
        int r = b - HIST_B - CVT_B;
        int j = 0, acc = 0;
        for (; j < 12; ++j) {
            int nb = (a.tj[j].K * a.tj[j].N) >> 8;
            if (r < acc + nb) break;
            acc += nb;
        }
        TJob jb = a.tj[j];
        int e = (r - acc) * 256 + t;
        int k = e / jb.N, n = e - k * jb.N;
        jb.T[(size_t)n * jb.K + k] = f2bf(jb.W[e]);
    }
}

// ---- scan phase 1: per-block sums ----
__global__ __launch_bounds__(256) void scan1(const int* __restrict__ d, int* __restrict__ part, int n) {
    __shared__ int wsum[4];
    int b = blockIdx.x, t = threadIdx.x;
    int i0 = b * 2048 + t * 8;
    int s = 0;
#pragma unroll
    for (int k = 0; k < 8; ++k) s += (i0 + k < n) ? d[i0 + k] : 0;
#pragma unroll
    for (int off = 32; off > 0; off >>= 1) s += __shfl_down(s, off, 64);
    if ((t & 63) == 0) wsum[t >> 6] = s;
    __syncthreads();
    if (t == 0) part[b] = wsum[0] + wsum[1] + wsum[2] + wsum[3];
}

// ---- scan phase 2: block-local scan; each block redundantly scans partials ----
__global__ __launch_bounds__(256) void scan3(int* __restrict__ d, const int* __restrict__ part,
                                             int n, int nb) {
    __shared__ int wsum[4];
    __shared__ int blockoff_sh;
    int b = blockIdx.x, t = threadIdx.x;
    int lane = t & 63, wv = t >> 6;
    if (t < 64) {
        int v = (t < nb) ? part[t] : 0;
        int incl = v;
#pragma unroll
        for (int off = 1; off < 64; off <<= 1) {
            int tv = __shfl_up(incl, off, 64);
            if (t >= off) incl += tv;
        }
        if (t == b) blockoff_sh = incl - v;
    }
    int i0 = b * 2048 + t * 8;
    int v[8];
    int tsum = 0;
#pragma unroll
    for (int k = 0; k < 8; ++k) {
        v[k] = (i0 + k < n) ? d[i0 + k] : 0;
        tsum += v[k];
    }
    int incl = tsum;
#pragma unroll
    for (int off = 1; off < 64; off <<= 1) {
        int tv = __shfl_up(incl, off, 64);
        if (lane >= off) incl += tv;
    }
    if (lane == 63) wsum[wv] = incl;
    __syncthreads();
    int woff = 0;
    for (int w = 0; w < wv; ++w) woff += wsum[w];
    int run = blockoff_sh + woff + (incl - tsum);
#pragma unroll
    for (int k = 0; k < 8; ++k) {
        if (i0 + k < n) d[i0 + k] = run;
        run += v[k];
    }
}

// ---- sharded CSR fill ----
__global__ __launch_bounds__(256) void fill2(const int* __restrict__ eui,
                                             const int* __restrict__ eiu,
                                             int* __restrict__ rp_i, int* __restrict__ rp_u,
                                             int* __restrict__ csr) {
    const int* src = blockIdx.y ? eiu : eui;
    const int* dst = src + NE;
    int* rp = blockIdx.y ? rp_u : rp_i;
    const int sh = blockIdx.x & 7;
    const int chunk = blockIdx.x >> 3;
    const int lo = sh * NODES_PER, hi = lo + NODES_PER;
    const int end = (chunk + 1) * FCHUNK_SZ;
    for (int i = chunk * FCHUNK_SZ + threadIdx.x; i < end; i += 256) {
        int d = dst[i];
        if (d >= lo && d < hi) {
            int p = atomicAdd(&rp[d], 1);
            csr[p] = src[i];
        }
    }
}

// ================= gather mean aggregation (bf16, fp32 accum), 2 jobs =================
// D==256: one wave per row, uint2/lane, unroll 8 (8 x 512B gathers in flight).
// D==128: TWO rows per wave (32 lanes x uint2 each); each 512B load serves 2 edges.
struct AggJob { const int* endptr; const int* csr; int s0_first; const ushort_t* x; ushort_t* out; int n; };
struct AggJobs2 { AggJob j[2]; };

template <int D>
__global__ __launch_bounds__(256) void agg2(AggJobs2 js) {
    AggJob jb = js.j[blockIdx.y];
    int wave = (int)((blockIdx.x * 256u + threadIdx.x) >> 6);
    int lane = threadIdx.x & 63;

    if constexpr (D == 256) {
        int w = wave;
        if (w >= jb.n) return;
        int s0 = (w == 0) ? jb.s0_first : jb.endptr[w - 1];
        int cnt = jb.endptr[w] - s0;
        float sc = (cnt > 0) ? 1.0f / (float)cnt : 0.0f;
        const uint2* xp = (const uint2*)jb.x;  // row = 64 uint2
        float f0 = 0.f, f1 = 0.f, f2 = 0.f, f3 = 0.f;
        float g0 = 0.f, g1 = 0.f, g2 = 0.f, g3 = 0.f;
        for (int chunk = 0; chunk < cnt; chunk += 64) {
            int m = cnt - chunk;
            if (m > 64) m = 64;
            int vidx = jb.csr[s0 + chunk + ((lane < m) ? lane : (m - 1))];
            int j = 0;
            for (; j + 7 < m; j += 8) {
                int i0 = __shfl(vidx, j, 64);
                int i1 = __shfl(vidx, j + 1, 64);
                int i2 = __shfl(vidx, j + 2, 64);
                int i3 = __shfl(vidx, j + 3, 64);
                int i4 = __shfl(vidx, j + 4, 64);
                int i5 = __shfl(vidx, j + 5, 64);
                int i6 = __shfl(vidx, j + 6, 64);
                int i7 = __shfl(vidx, j + 7, 64);
                uint2 v0 = xp[(size_t)i0 * 64 + lane];
                uint2 v1 = xp[(size_t)i1 * 64 + lane];
                uint2 v2 = xp[(size_t)i2 * 64 + lane];
                uint2 v3 = xp[(size_t)i3 * 64 + lane];
                uint2 v4 = xp[(size_t)i4 * 64 + lane];
                uint2 v5 = xp[(size_t)i5 * 64 + lane];
                uint2 v6 = xp[(size_t)i6 * 64 + lane];
                uint2 v7 = xp[(size_t)i7 * 64 + lane];
                f0 += (bf_lo(v0.x) + bf_lo(v2.x)) + (bf_lo(v4.x) + bf_lo(v6.x));
                f1 += (bf_hi(v0.x) + bf_hi(v2.x)) + (bf_hi(v4.x) + bf_hi(v6.x));
                f2 += (bf_lo(v0.y) + bf_lo(v2.y)) + (bf_lo(v4.y) + bf_lo(v6.y));
                f3 += (bf_hi(v0.y) + bf_hi(v2.y)) + (bf_hi(v4.y) + bf_hi(v6.y));
                g0 += (bf_lo(v1.x) + bf_lo(v3.x)) + (bf_lo(v5.x) + bf_lo(v7.x));
                g1 += (bf_hi(v1.x) + bf_hi(v3.x)) + (bf_hi(v5.x) + bf_hi(v7.x));
                g2 += (bf_lo(v1.y) + bf_lo(v3.y)) + (bf_lo(v5.y) + bf_lo(v7.y));
                g3 += (bf_hi(v1.y) + bf_hi(v3.y)) + (bf_hi(v5.y) + bf_hi(v7.y));
            }
            for (; j < m; ++j) {
                int i0 = __shfl(vidx, j, 64);
                uint2 v0 = xp[(size_t)i0 * 64 + lane];
                f0 += bf_lo(v0.x); f1 += bf_hi(v0.x);
                f2 += bf_lo(v0.y); f3 += bf_hi(v0.y);
            }
        }
        uint2 o;
        o.x = (unsigned int)f2bf((f0 + g0) * sc) | ((unsigned int)f2bf((f1 + g1) * sc) << 16);
        o.y = (unsigned int)f2bf((f2 + g2) * sc) | ((unsigned int)f2bf((f3 + g3) * sc) << 16);
        ((uint2*)jb.out)[(size_t)w * 64 + lane] = o;
    } else {
        // D == 128: halves of the wave process two adjacent dst rows (n is even).
        const int l = lane & 31;
        const int h = lane >> 5;
        int w2 = wave * 2;
        if (w2 >= jb.n) return;
        int w = w2 + h;
        int s0 = (w == 0) ? jb.s0_first : jb.endptr[w - 1];
        int cnt = jb.endptr[w] - s0;
        float sc = (cnt > 0) ? 1.0f / (float)cnt : 0.0f;
        int cother = __shfl_xor(cnt, 32, 64);
        int cmax = (cnt > cother) ? cnt : cother;
        const uint2* xp = (const uint2*)jb.x;  // row = 32 uint2
        float f0 = 0.f, f1 = 0.f, f2 = 0.f, f3 = 0.f;
        float g0 = 0.f, g1 = 0.f, g2 = 0.f, g3 = 0.f;
        for (int chunk = 0; chunk < cmax; chunk += 32) {
            int mh = cnt - chunk;  // this half's remaining (may be <= 0)
            int safe = (mh > 0) ? ((l < mh) ? l : mh - 1) : 0;
            int vidx = jb.csr[s0 + chunk + safe];
            int mm = cmax - chunk;
            if (mm > 32) mm = 32;
            int j = 0;
            for (; j + 3 < mm; j += 4) {
                int i0 = __shfl(vidx, j, 32);
                int i1 = __shfl(vidx, j + 1, 32);
                int i2 = __shfl(vidx, j + 2, 32);
                int i3 = __shfl(vidx, j + 3, 32);
                float m0 = (j < mh) ? 1.f : 0.f;
                float m1 = (j + 1 < mh) ? 1.f : 0.f;
                float m2 = (j + 2 < mh) ? 1.f : 0.f;
                float m3 = (j + 3 < mh) ? 1.f : 0.f;
                uint2 u0 = xp[(size_t)((j < mh) ? i0 : 0) * 32 + l];
                uint2 u1 = xp[(size_t)((j + 1 < mh) ? i1 : 0) * 32 + l];
                uint2 u2 = xp[(size_t)((j + 2 < mh) ? i2 : 0) * 32 + l];
                uint2 u3 = xp[(size_t)((j + 3 < mh) ? i3 : 0) * 32 + l];
                f0 = fmaf(m0, bf_lo(u0.x), f0); f1 = fmaf(m0, bf_hi(u0.x), f1);
                f2 = fmaf(m0, bf_lo(u0.y), f2); f3 = fmaf(m0, bf_hi(u0.y), f3);
                g0 = fmaf(m1, bf_lo(u1.x), g0); g1 = fmaf(m1, bf_hi(u1.x), g1);
                g2 = fmaf(m1, bf_lo(u1.y), g2); g3 = fmaf(m1, bf_hi(u1.y), g3);
                f0 = fmaf(m2, bf_lo(u2.x), f0); f1 = fmaf(m2, bf_hi(u2.x), f1);
                f2 = fmaf(m2, bf_lo(u2.y), f2); f3 = fmaf(m2, bf_hi(u2.y), f3);
                g0 = fmaf(m3, bf_lo(u3.x), g0); g1 = fmaf(m3, bf_hi(u3.x), g1);
                g2 = fmaf(m3, bf_lo(u3.y), g2); g3 = fmaf(m3, bf_hi(u3.y), g3);
            }
            for (; j < mm; ++j) {
                int i0 = __shfl(vidx, j, 32);
                float m0 = (j < mh) ? 1.f : 0.f;
                uint2 u0 = xp[(size_t)((j < mh) ? i0 : 0) * 32 + l];
                f0 = fmaf(m0, bf_lo(u0.x), f0); f1 = fmaf(m0, bf_hi(u0.x), f1);
                f2 = fmaf(m0, bf_lo(u0.y), f2); f3 = fmaf(m0, bf_hi(u0.y), f3);
            }
        }
        uint2 o;
        o.x = (unsigned int)f2bf((f0 + g0) * sc) | ((unsigned int)f2bf((f1 + g1) * sc) << 16);
        o.y = (unsigned int)f2bf((f2 + g2) * sc) | ((unsigned int)f2bf((f3 + g3) * sc) << 16);
        ((uint2*)jb.out)[(size_t)w * 32 + l] = o;
    }
}

// ================= MFMA GEMM: C = A1@W1 + A2@W2 + bias, 2 jobs via blockIdx.z =================
struct GemmJob {
    const ushort_t *A1, *W1T;
    int K1;
    const ushort_t *A2, *W2T;
    int K2;
    const float* bias;
    void* C;
};
struct GemmJobs2 { GemmJob j[2]; };

template <typename OutT>
__global__ __launch_bounds__(256) void gemm2(GemmJobs2 js, int M, int N) {
    GemmJob jb = js.j[blockIdx.z];
    __shared__ ushort_t sA[128 * 32];
    __shared__ ushort_t sB[128 * 32];
    const int tid = threadIdx.x;
    const int lane = tid & 63;
    const int wv = tid >> 6;
    const int wm = wv & 1, wn = wv >> 1;
    const int bm = blockIdx.y * 128, bn = blockIdx.x * 128;

    f32x4 acc[4][4] = {};

    const int srow = tid >> 2;
    const int scol = (tid & 3) * 8;

    for (int part = 0; part < 2; ++part) {
        const ushort_t* A = part ? jb.A2 : jb.A1;
        const ushort_t* WT = part ? jb.W2T : jb.W1T;
        const int K = part ? jb.K2 : jb.K1;
        int ar0 = bm + srow;       if (ar0 > M - 1) ar0 = M - 1;
        int ar1 = bm + 64 + srow;  if (ar1 > M - 1) ar1 = M - 1;
        const size_t aoff0 = (size_t)ar0 * K + scol;
        const size_t aoff1 = (size_t)ar1 * K + scol;
        const size_t boff0 = (size_t)(bn + srow) * K + scol;
        const size_t boff1 = (size_t)(bn + 64 + srow) * K + scol;
        for (int k0 = 0; k0 < K; k0 += 32) {
            __syncthreads();
            load_lds16(A + aoff0 + k0, sA + tid * 8);
            load_lds16(A + aoff1 + k0, sA + 2048 + tid * 8);
            load_lds16(WT + boff0 + k0, sB + tid * 8);
            load_lds16(WT + boff1 + k0, sB + 2048 + tid * 8);
            __syncthreads();
            const ushort_t* pA = sA + ((wm * 64 + (lane & 15)) * 32 + (lane >> 4) * 8);
            const ushort_t* pB = sB + ((wn * 64 + (lane & 15)) * 32 + (lane >> 4) * 8);
            bf16x8 af[4], bfr[4];
#pragma unroll
            for (int mt = 0; mt < 4; ++mt) af[mt] = *(const bf16x8*)(pA + mt * 512);
#pragma unroll
            for (int nt = 0; nt < 4; ++nt) bfr[nt] = *(const bf16x8*)(pB + nt * 512);
#pragma unroll
            for (int mt = 0; mt < 4; ++mt)
#pragma unroll
                for (int nt = 0; nt < 4; ++nt)
                    acc[mt][nt] = __builtin_amdgcn_mfma_f32_16x16x32_bf16(
                        af[mt], bfr[nt], acc[mt][nt], 0, 0, 0);
        }
    }

#pragma unroll
    for (int mt = 0; mt < 4; ++mt) {
#pragma unroll
        for (int r = 0; r < 4; ++r) {
            int row = bm + wm * 64 + mt * 16 + (lane >> 4) * 4 + r;
            if (row >= M) continue;
#pragma unroll
            for (int nt = 0; nt < 4; ++nt) {
                int col = bn + wn * 64 + nt * 16 + (lane & 15);
                float v = acc[mt][nt][r] + jb.bias[col];
                if constexpr (sizeof(OutT) == 2)
                    ((ushort_t*)jb.C)[(size_t)row * N + col] = f2bf(v);
                else
                    ((float*)jb.C)[(size_t)row * N + col] = v;
            }
        }
    }
}

// ================= decode: bf16 z, 4 edges per wave (16-lane quarters, uint4) =================
__global__ void decode_kernel(const int* __restrict__ lbl, const ushort_t* __restrict__ zu,
                              const ushort_t* __restrict__ zi, float* __restrict__ out, int n) {
    int gid = blockIdx.x * blockDim.x + threadIdx.x;
    int wave = gid >> 6;
    int lane = threadIdx.x & 63;
    int q = lane >> 4;
    int l = lane & 15;
    int e = wave * 4 + q;
    if (e >= n) return;
    int u = lbl[e];
    int it = lbl[n + e];
    // row = 128 bf16 = 16 x uint4
    uint4 a = ((const uint4*)zu)[(size_t)u * 16 + l];
    uint4 b = ((const uint4*)zi)[(size_t)it * 16 + l];
    float s = bf_lo(a.x) * bf_lo(b.x) + bf_hi(a.x) * bf_hi(b.x) +
              bf_lo(a.y) * bf_lo(b.y) + bf_hi(a.y) * bf_hi(b.y) +
              bf_lo(a.z) * bf_lo(b.z) + bf_hi(a.z) * bf_hi(b.z) +
              bf_lo(a.w) * bf_lo(b.w) + bf_hi(a.w) * bf_hi(b.w);
#pragma unroll
    for (int off = 8; off > 0; off >>= 1) s += __shfl_down(s, off, 16);
    if (l == 0) out[e] = s;
}

extern "C" void kernel_launch(void* const* d_in, const int* in_sizes, int n_in,
                              void* d_out, int out_size, void* d_ws, size_t ws_size,
                              hipStream_t stream) {
    const float* x_user = (const float*)d_in[0];
    const float* x_item = (const float*)d_in[1];
    const int* edge_ui = (const int*)d_in[2];   // row0=src(user), row1=dst(item)
    const int* edge_iu = (const int*)d_in[3];   // row0=src(item), row1=dst(user)
    const int* edge_lbl = (const int*)d_in[4];
    const float* w_msg_ui0 = (const float*)d_in[5];
    const float* b_ui0 = (const float*)d_in[6];
    const float* w_root_ui0 = (const float*)d_in[7];
    const float* w_msg_iu0 = (const float*)d_in[8];
    const float* b_iu0 = (const float*)d_in[9];
    const float* w_root_iu0 = (const float*)d_in[10];
    const float* w_msg_ui1 = (const float*)d_in[11];
    const float* b_ui1 = (const float*)d_in[12];
    const float* w_root_ui1 = (const float*)d_in[13];
    const float* w_msg_iu1 = (const float*)d_in[14];
    const float* b_iu1 = (const float*)d_in[15];
    const float* w_root_iu1 = (const float*)d_in[16];
    const float* w_lin_u = (const float*)d_in[17];  // [512,128]
    const float* b_lin_u = (const float*)d_in[18];
    const float* w_lin_i = (const float*)d_in[19];
    const float* b_lin_i = (const float*)d_in[20];
    float* out = (float*)d_out;

    // ---- workspace layout ----
    char* p = (char*)d_ws;
    ushort_t* user0 = (ushort_t*)p;  p += (size_t)NU * HID * 2;
    ushort_t* item0 = (ushort_t*)p;  p += (size_t)NI * HID * 2;
    ushort_t* user1 = (ushort_t*)p;  p += (size_t)NU * HID * 2;
    ushort_t* item1 = (ushort_t*)p;  p += (size_t)NI * HID * 2;
    ushort_t* mean_a = (ushort_t*)p; p += (size_t)NI * HID * 2;
    ushort_t* mean_b = (ushort_t*)p; p += (size_t)NU * HID * 2;
    ushort_t* xb_u  = (ushort_t*)p;  p += (size_t)NU * DIN * 2;
    ushort_t* xb_i  = (ushort_t*)p;  p += (size_t)NI * DIN * 2;
    ushort_t* z_user = (ushort_t*)p; p += (size_t)NU * DOUT * 2;
    ushort_t* z_item = (ushort_t*)p; p += (size_t)NI * DOUT * 2;
    int* cnt_i      = (int*)p;       p += (size_t)NI * 4;
    int* cnt_u      = (int*)p;       p += (size_t)NU * 4;   // contiguous after cnt_i
    int* csr        = (int*)p;       p += (size_t)2 * NE * 4;  // [0,NE): ui; [NE,2NE): iu
    int* scan_part  = (int*)p;       p += 64 * 4;
    ushort_t* T_msg_ui0 = (ushort_t*)p; p += (size_t)DIN * HID * 2;
    ushort_t* T_root_ui0 = (ushort_t*)p; p += (size_t)DIN * HID * 2;
    ushort_t* T_msg_iu0 = (ushort_t*)p; p += (size_t)DIN * HID * 2;
    ushort_t* T_root_iu0 = (ushort_t*)p; p += (size_t)DIN * HID * 2;
    ushort_t* T_msg_ui1 = (ushort_t*)p; p += (size_t)HID * HID * 2;
    ushort_t* T_root_ui1 = (ushort_t*)p; p += (size_t)HID * HID * 2;
    ushort_t* T_msg_iu1 = (ushort_t*)p; p += (size_t)HID * HID * 2;
    ushort_t* T_root_iu1 = (ushort_t*)p; p += (size_t)HID * HID * 2;
    ushort_t* T_lin_u_a = (ushort_t*)p; p += (size_t)HID * DOUT * 2;
    ushort_t* T_lin_u_b = (ushort_t*)p; p += (size_t)HID * DOUT * 2;
    ushort_t* T_lin_i_a = (ushort_t*)p; p += (size_t)HID * DOUT * 2;
    ushort_t* T_lin_i_b = (ushort_t*)p; p += (size_t)HID * DOUT * 2;

    const int NCNT = NI + NU;
    const int NB = (NCNT + 2047) / 2048;  // 49

    // ---- fused prep (hist + cvt + transpose) ----
    hipMemsetAsync(cnt_i, 0, (size_t)NCNT * sizeof(int), stream);
    PrepArgs pa;
    pa.dui = edge_ui + NE; pa.diu = edge_iu + NE; pa.cnt_i = cnt_i; pa.cnt_u = cnt_u;
    pa.xu = x_user; pa.xbu = xb_u; pa.xi = x_item; pa.xbi = xb_i;
    TJob tj[12] = {
        {w_msg_ui0, T_msg_ui0, DIN, HID}, {w_root_ui0, T_root_ui0, DIN, HID},
        {w_msg_iu0, T_msg_iu0, DIN, HID}, {w_root_iu0, T_root_iu0, DIN, HID},
        {w_msg_ui1, T_msg_ui1, HID, HID}, {w_root_ui1, T_root_ui1, HID, HID},
        {w_msg_iu1, T_msg_iu1, HID, HID}, {w_root_iu1, T_root_iu1, HID, HID},
        {w_lin_u, T_lin_u_a, HID, DOUT}, {w_lin_u + (size_t)HID * DOUT, T_lin_u_b, HID, DOUT},
        {w_lin_i, T_lin_i_a, HID, DOUT}, {w_lin_i + (size_t)HID * DOUT, T_lin_i_b, HID, DOUT},
    };
    for (int j = 0; j < 12; ++j) pa.tj[j] = tj[j];
    prep_kernel<<<HIST_B + CVT_B + TR_B, 256, 0, stream>>>(pa);

    // ---- scan + fill ----
    scan1<<<NB, 256, 0, stream>>>(cnt_i, scan_part, NCNT);
    scan3<<<NB, 256, 0, stream>>>(cnt_i, scan_part, NCNT, NB);
    fill2<<<dim3(NSHARD * FCHUNKS, 2), 256, 0, stream>>>(edge_ui, edge_iu, cnt_i, cnt_u, csr);
    // cnt_i/cnt_u now hold absolute row END offsets into csr.

    // ---- layer 0 ----
    {
        AggJobs2 aj = {{{cnt_i, csr, 0, xb_u, mean_a, NI},
                        {cnt_u, csr, NE, xb_i, mean_b, NU}}};
        agg2<DIN><<<dim3((NI / 2 * 64) / 256, 2), 256, 0, stream>>>(aj);
        GemmJobs2 gj = {{{mean_a, T_msg_ui0, DIN, xb_i, T_root_ui0, DIN, b_ui0, item0},
                         {mean_b, T_msg_iu0, DIN, xb_u, T_root_iu0, DIN, b_iu0, user0}}};
        gemm2<ushort_t><<<dim3(HID / 128, (NI + 127) / 128, 2), 256, 0, stream>>>(gj, NI, HID);
    }

    // ---- layer 1 ----
    {
        AggJobs2 aj = {{{cnt_i, csr, 0, user0, mean_a, NI},
                        {cnt_u, csr, NE, item0, mean_b, NU}}};
        agg2<HID><<<dim3((NI + 3) / 4, 2), 256, 0, stream>>>(aj);
        GemmJobs2 gj = {{{mean_a, T_msg_ui1, HID, item0, T_root_ui1, HID, b_ui1, item1},
                         {mean_b, T_msg_iu1, HID, user0, T_root_iu1, HID, b_iu1, user1}}};
        gemm2<ushort_t><<<dim3(HID / 128, (NI + 127) / 128, 2), 256, 0, stream>>>(gj, NI, HID);
    }

    // ---- JK concat + per-type linear ----
    {
        GemmJobs2 gj = {{{user0, T_lin_u_a, HID, user1, T_lin_u_b, HID, b_lin_u, z_user},
                         {item0, T_lin_i_a, HID, item1, T_lin_i_b, HID, b_lin_i, z_item}}};
        gemm2<ushort_t><<<dim3(DOUT / 128, (NU + 127) / 128, 2), 256, 0, stream>>>(gj, NU, DOUT);
    }

    // ---- decode (4 edges per wave) ----
    decode_kernel<<<(((NLBL + 3) / 4) * 64 + 255) / 256, 256, 0, stream>>>(
        edge_lbl, z_user, z_item, out, NLBL);
}